// Round 1
// baseline (733.545 us; speedup 1.0000x reference)
//
#include <hip/hip_runtime.h>
#include <cstdint>

// Transformer block: B=16, S=1024, E=256, H=4, D=64. fp32 in/out.
// T = B*S = 16384 tokens.
//
// Pipeline:
//  1. h   = LN1(x)                      -> buf0 [T,256]
//  2. qkv = h @ qkv_w + qkv_b           -> buf1 [T,768]
//  3. o   = causal_attn(qkv)            -> buf0 [T,256]   (heads fused back)
//  4. x1  = x + o @ out_w + out_b       -> d_out [T,256]
//  5. h2  = LN2(x1)                     -> buf0 [T,256]
//  6. h3  = relu(h2 @ fc_w + fc_b)      -> buf1 [T,1024]
//  7. out = x1 + h3 @ proj_w + proj_b   -> d_out (in-place residual)

// ---------------------------------------------------------------- LayerNorm
// One wave (64 lanes) per 256-float row; 4 rows per 256-thread block.
__global__ __launch_bounds__(256) void ln_kernel(const float* __restrict__ x,
                                                 const float* __restrict__ gamma,
                                                 const float* __restrict__ beta,
                                                 float* __restrict__ out)
{
    int tid  = threadIdx.x;
    int lane = tid & 63;
    int row  = blockIdx.x * 4 + (tid >> 6);
    const float* xr = x + (size_t)row * 256;
    float4 v = *reinterpret_cast<const float4*>(xr + lane * 4);

    float s = v.x + v.y + v.z + v.w;
#pragma unroll
    for (int o = 32; o >= 1; o >>= 1) s += __shfl_xor(s, o);
    float mu = s * (1.0f / 256.0f);

    float dx = v.x - mu, dy = v.y - mu, dz = v.z - mu, dw = v.w - mu;
    float q = dx * dx + dy * dy + dz * dz + dw * dw;
#pragma unroll
    for (int o = 32; o >= 1; o >>= 1) q += __shfl_xor(q, o);
    float rstd = rsqrtf(q * (1.0f / 256.0f) + 1e-5f);

    float4 gv = *reinterpret_cast<const float4*>(gamma + lane * 4);
    float4 bv = *reinterpret_cast<const float4*>(beta + lane * 4);
    float4 ov;
    ov.x = dx * rstd * gv.x + bv.x;
    ov.y = dy * rstd * gv.y + bv.y;
    ov.z = dz * rstd * gv.z + bv.z;
    ov.w = dw * rstd * gv.w + bv.w;
    *reinterpret_cast<float4*>(out + (size_t)row * 256 + lane * 4) = ov;
}

// ---------------------------------------------------------------- GEMM
// C[M,N] = op(A[M,K] @ W[K,N] + bias [+ residual]) ; op = relu optional.
// 64x64 block tile, 256 threads, 4x4 per thread, K-step 16.
// M,N multiples of 64; K multiple of 16 (here K in {256,1024}).
template <int RELU, int RES>
__global__ __launch_bounds__(256) void gemm_kernel(const float* __restrict__ A,
                                                   const float* __restrict__ W,
                                                   const float* __restrict__ bias,
                                                   const float* __restrict__ R,
                                                   float* __restrict__ C,
                                                   int N, int K)
{
    __shared__ float As[64][17];   // [m][k], pad 17 -> write/read aliasing <=2-way
    __shared__ float Bs[16][64];   // [k][n]

    int tid = threadIdx.x;
    int tn  = tid & 15;            // col group (4 cols)
    int tm  = tid >> 4;            // row group (4 rows)
    int bm  = blockIdx.y * 64;
    int bn  = blockIdx.x * 64;

    int arow = tid >> 2;           // 0..63
    int akc  = (tid & 3) << 2;     // 0,4,8,12
    int brow = tid >> 4;           // 0..15
    int bcol = (tid & 15) << 2;    // 0..60

    float acc[4][4] = {};

    const float* Aptr = A + (size_t)(bm + arow) * K + akc;
    const float* Wptr = W + (size_t)brow * N + bn + bcol;

    for (int k0 = 0; k0 < K; k0 += 16) {
        float4 av = *reinterpret_cast<const float4*>(Aptr + k0);
        float4 bv = *reinterpret_cast<const float4*>(Wptr + (size_t)k0 * N);
        __syncthreads();           // previous iter's LDS reads complete
        As[arow][akc + 0] = av.x;
        As[arow][akc + 1] = av.y;
        As[arow][akc + 2] = av.z;
        As[arow][akc + 3] = av.w;
        *reinterpret_cast<float4*>(&Bs[brow][bcol]) = bv;
        __syncthreads();

#pragma unroll
        for (int k = 0; k < 16; ++k) {
            float a[4], b[4];
#pragma unroll
            for (int i = 0; i < 4; ++i) a[i] = As[tm * 4 + i][k];
#pragma unroll
            for (int j = 0; j < 4; ++j) b[j] = Bs[k][tn * 4 + j];
#pragma unroll
            for (int i = 0; i < 4; ++i)
#pragma unroll
                for (int j = 0; j < 4; ++j) acc[i][j] += a[i] * b[j];
        }
    }

    int c = bn + tn * 4;
    float4 bb = *reinterpret_cast<const float4*>(bias + c);
#pragma unroll
    for (int i = 0; i < 4; ++i) {
        int r = bm + tm * 4 + i;
        float4 ov;
        ov.x = acc[i][0] + bb.x;
        ov.y = acc[i][1] + bb.y;
        ov.z = acc[i][2] + bb.z;
        ov.w = acc[i][3] + bb.w;
        if (RELU) {
            ov.x = fmaxf(ov.x, 0.0f); ov.y = fmaxf(ov.y, 0.0f);
            ov.z = fmaxf(ov.z, 0.0f); ov.w = fmaxf(ov.w, 0.0f);
        }
        if (RES) {
            float4 rv = *reinterpret_cast<const float4*>(R + (size_t)r * N + c);
            ov.x += rv.x; ov.y += rv.y; ov.z += rv.z; ov.w += rv.w;
        }
        *reinterpret_cast<float4*>(C + (size_t)r * N + c) = ov;
    }
}

// ---------------------------------------------------------------- Attention
// Flash-style causal attention. qkv layout [B,S,768]: q at col h*64,
// k at 256+h*64, v at 512+h*64. One block per (qt, h, b); 64 queries/block.
// Output o as [T,256] with head h at columns h*64..h*64+63.
__global__ __launch_bounds__(256) void attn_kernel(const float* __restrict__ qkv,
                                                   float* __restrict__ o)
{
    __shared__ float Qs[64][65];   // odd pad: scalar reads <=2-way
    __shared__ float Ks[64][65];
    __shared__ float Vs[64][68];   // pad 68: float4 reads, 16B aligned
    __shared__ float Ps[64][66];
    __shared__ float mS[64], lS[64];

    int tid = threadIdx.x;
    int qt = blockIdx.x, h = blockIdx.y, b = blockIdx.z;
    const float* base = qkv + (size_t)b * 1024 * 768;

    int lr = tid >> 4;             // 0..15
    int lc = (tid & 15) << 2;      // 0..60

    // load Q tile, pre-scaled by 1/sqrt(64)
#pragma unroll
    for (int i = 0; i < 4; ++i) {
        int r = lr + i * 16;
        const float* p = base + (size_t)(qt * 64 + r) * 768 + h * 64 + lc;
        float4 v = *reinterpret_cast<const float4*>(p);
        Qs[r][lc + 0] = v.x * 0.125f;
        Qs[r][lc + 1] = v.y * 0.125f;
        Qs[r][lc + 2] = v.z * 0.125f;
        Qs[r][lc + 3] = v.w * 0.125f;
    }
    if (tid < 64) { mS[tid] = -1e30f; lS[tid] = 0.0f; }

    float acc[16];
#pragma unroll
    for (int j = 0; j < 16; ++j) acc[j] = 0.0f;

    int q       = tid >> 2;        // output query row owned (0..63)
    int quarter = tid & 3;
    int dbase   = quarter * 16;    // owned d-range / owned k-range in softmax
    int sq0     = (tid >> 4) << 2; // scores: 4 q rows
    int sk0     = (tid & 15) << 2; // scores: 4 k cols

    for (int kt = 0; kt <= qt; ++kt) {
        __syncthreads();           // prior-iter Ps/Vs reads done
#pragma unroll
        for (int i = 0; i < 4; ++i) {
            int r = lr + i * 16;
            const float* pk = base + (size_t)(kt * 64 + r) * 768 + 256 + h * 64 + lc;
            const float* pv = base + (size_t)(kt * 64 + r) * 768 + 512 + h * 64 + lc;
            float4 kv = *reinterpret_cast<const float4*>(pk);
            float4 vv = *reinterpret_cast<const float4*>(pv);
            Ks[r][lc + 0] = kv.x; Ks[r][lc + 1] = kv.y;
            Ks[r][lc + 2] = kv.z; Ks[r][lc + 3] = kv.w;
            *reinterpret_cast<float4*>(&Vs[r][lc]) = vv;
        }
        __syncthreads();

        // scores: 4x4 per thread
        float s[4][4] = {};
#pragma unroll 4
        for (int d = 0; d < 64; ++d) {
            float qv[4], kv[4];
#pragma unroll
            for (int i = 0; i < 4; ++i) qv[i] = Qs[sq0 + i][d];
#pragma unroll
            for (int j = 0; j < 4; ++j) kv[j] = Ks[sk0 + j][d];
#pragma unroll
            for (int i = 0; i < 4; ++i)
#pragma unroll
                for (int j = 0; j < 4; ++j) s[i][j] += qv[i] * kv[j];
        }
        if (kt == qt) {
#pragma unroll
            for (int i = 0; i < 4; ++i)
#pragma unroll
                for (int j = 0; j < 4; ++j)
                    if (sk0 + j > sq0 + i) s[i][j] = -1e30f;
        }
#pragma unroll
        for (int i = 0; i < 4; ++i)
#pragma unroll
            for (int j = 0; j < 4; ++j) Ps[sq0 + i][sk0 + j] = s[i][j];
        __syncthreads();

        // online softmax: 4 threads per query row, 16 k each
        float p[16];
        float pmax = -1e30f;
#pragma unroll
        for (int j = 0; j < 16; ++j) {
            p[j] = Ps[q][dbase + j];
            pmax = fmaxf(pmax, p[j]);
        }
        pmax = fmaxf(pmax, __shfl_xor(pmax, 1));
        pmax = fmaxf(pmax, __shfl_xor(pmax, 2));
        float mold = mS[q];
        float mnew = fmaxf(mold, pmax);
        float f    = __expf(mold - mnew);
        float psum = 0.0f;
#pragma unroll
        for (int j = 0; j < 16; ++j) {
            p[j] = __expf(p[j] - mnew);
            psum += p[j];
            Ps[q][dbase + j] = p[j];
        }
        psum += __shfl_xor(psum, 1);
        psum += __shfl_xor(psum, 2);
        if (quarter == 0) { mS[q] = mnew; lS[q] = lS[q] * f + psum; }
#pragma unroll
        for (int j = 0; j < 16; ++j) acc[j] *= f;
        __syncthreads();           // Ps prob writes visible

        // PV: acc[q][dbase..dbase+15] += P[q][k] * V[k][d]
        for (int k = 0; k < 64; ++k) {
            float pk = Ps[q][k];
#pragma unroll
            for (int jj = 0; jj < 4; ++jj) {
                float4 v4 = *reinterpret_cast<const float4*>(&Vs[k][dbase + jj * 4]);
                acc[jj * 4 + 0] += pk * v4.x;
                acc[jj * 4 + 1] += pk * v4.y;
                acc[jj * 4 + 2] += pk * v4.z;
                acc[jj * 4 + 3] += pk * v4.w;
            }
        }
    }
    __syncthreads();

    float linv = 1.0f / lS[q];
    float* op = o + (size_t)(b * 1024 + qt * 64 + q) * 256 + h * 64 + dbase;
#pragma unroll
    for (int jj = 0; jj < 4; ++jj) {
        float4 ov;
        ov.x = acc[jj * 4 + 0] * linv;
        ov.y = acc[jj * 4 + 1] * linv;
        ov.z = acc[jj * 4 + 2] * linv;
        ov.w = acc[jj * 4 + 3] * linv;
        *reinterpret_cast<float4*>(op + jj * 4) = ov;
    }
}

// ---------------------------------------------------------------- launch
extern "C" void kernel_launch(void* const* d_in, const int* in_sizes, int n_in,
                              void* d_out, int out_size, void* d_ws, size_t ws_size,
                              hipStream_t stream)
{
    const float* x      = (const float*)d_in[0];
    const float* qkv_w  = (const float*)d_in[1];
    const float* qkv_b  = (const float*)d_in[2];
    const float* out_w  = (const float*)d_in[3];
    const float* out_b  = (const float*)d_in[4];
    const float* fc_w   = (const float*)d_in[5];
    const float* fc_b   = (const float*)d_in[6];
    const float* proj_w = (const float*)d_in[7];
    const float* proj_b = (const float*)d_in[8];
    const float* ln1_g  = (const float*)d_in[9];
    const float* ln1_b  = (const float*)d_in[10];
    const float* ln2_g  = (const float*)d_in[11];
    const float* ln2_b  = (const float*)d_in[12];
    float* out = (float*)d_out;

    float* buf0 = (float*)d_ws;            // h / o / h2 : 16384*256 floats
    float* buf1 = buf0 + 4194304;          // qkv / h3   : up to 16384*1024 floats

    dim3 blk(256);

    // 1. h = LN1(x)
    ln_kernel<<<dim3(4096), blk, 0, stream>>>(x, ln1_g, ln1_b, buf0);
    // 2. qkv = h @ qkv_w + qkv_b
    gemm_kernel<0, 0><<<dim3(768 / 64, 256), blk, 0, stream>>>(
        buf0, qkv_w, qkv_b, nullptr, buf1, 768, 256);
    // 3. o = attention(qkv)
    attn_kernel<<<dim3(16, 4, 16), blk, 0, stream>>>(buf1, buf0);
    // 4. x1 = x + o @ out_w + out_b   -> d_out
    gemm_kernel<0, 1><<<dim3(256 / 64, 256), blk, 0, stream>>>(
        buf0, out_w, out_b, x, out, 256, 256);
    // 5. h2 = LN2(x1)
    ln_kernel<<<dim3(4096), blk, 0, stream>>>(out, ln2_g, ln2_b, buf0);
    // 6. h3 = relu(h2 @ fc_w + fc_b)
    gemm_kernel<1, 0><<<dim3(1024 / 64, 256), blk, 0, stream>>>(
        buf0, fc_w, fc_b, nullptr, buf1, 1024, 256);
    // 7. out = x1 + h3 @ proj_w + proj_b   (in-place residual on d_out)
    gemm_kernel<0, 1><<<dim3(256 / 64, 256), blk, 0, stream>>>(
        buf1, proj_w, proj_b, out, out, 256, 1024);
}

// Round 2
// 454.957 us; speedup vs baseline: 1.6123x; 1.6123x over previous
//
#include <hip/hip_runtime.h>
#include <cstdint>

// Transformer block: B=16, S=1024, E=256, H=4, D=64. fp32 in/out.
// T = B*S = 16384 tokens.
//
// Pipeline:
//  1. h   = LN1(x)                      -> buf0 [T,256]
//  2. qkv = h @ qkv_w + qkv_b           -> buf1 [T,768]
//  3. o   = causal_attn(qkv)            -> buf0 [T,256]   (bf16 MFMA flash)
//  4. x1  = x + o @ out_w + out_b       -> d_out [T,256]
//  5. h2  = LN2(x1)                     -> buf0 [T,256]
//  6. h3  = relu(h2 @ fc_w + fc_b)      -> buf1 [T,1024]
//  7. out = x1 + h3 @ proj_w + proj_b   -> d_out (in-place residual)

using f32x4 = __attribute__((ext_vector_type(4))) float;
using s16x8 = __attribute__((ext_vector_type(8))) short;
using s16x4 = __attribute__((ext_vector_type(4))) short;

__device__ inline short f2bf(float f) {
    union { float f; unsigned u; } v{f};
    unsigned r = (v.u + 0x7FFFu + ((v.u >> 16) & 1u)) >> 16;   // RNE
    return (short)r;
}

// ---------------------------------------------------------------- LayerNorm
__global__ __launch_bounds__(256) void ln_kernel(const float* __restrict__ x,
                                                 const float* __restrict__ gamma,
                                                 const float* __restrict__ beta,
                                                 float* __restrict__ out)
{
    int tid  = threadIdx.x;
    int lane = tid & 63;
    int row  = blockIdx.x * 4 + (tid >> 6);
    const float* xr = x + (size_t)row * 256;
    float4 v = *reinterpret_cast<const float4*>(xr + lane * 4);

    float s = v.x + v.y + v.z + v.w;
#pragma unroll
    for (int o = 32; o >= 1; o >>= 1) s += __shfl_xor(s, o);
    float mu = s * (1.0f / 256.0f);

    float dx = v.x - mu, dy = v.y - mu, dz = v.z - mu, dw = v.w - mu;
    float q = dx * dx + dy * dy + dz * dz + dw * dw;
#pragma unroll
    for (int o = 32; o >= 1; o >>= 1) q += __shfl_xor(q, o);
    float rstd = rsqrtf(q * (1.0f / 256.0f) + 1e-5f);

    float4 gv = *reinterpret_cast<const float4*>(gamma + lane * 4);
    float4 bv = *reinterpret_cast<const float4*>(beta + lane * 4);
    float4 ov;
    ov.x = dx * rstd * gv.x + bv.x;
    ov.y = dy * rstd * gv.y + bv.y;
    ov.z = dz * rstd * gv.z + bv.z;
    ov.w = dw * rstd * gv.w + bv.w;
    *reinterpret_cast<float4*>(out + (size_t)row * 256 + lane * 4) = ov;
}

// ---------------------------------------------------------------- GEMM (fp32)
template <int RELU, int RES>
__global__ __launch_bounds__(256) void gemm_kernel(const float* __restrict__ A,
                                                   const float* __restrict__ W,
                                                   const float* __restrict__ bias,
                                                   const float* __restrict__ R,
                                                   float* __restrict__ C,
                                                   int N, int K)
{
    __shared__ float As[64][17];
    __shared__ float Bs[16][64];

    int tid = threadIdx.x;
    int tn  = tid & 15;
    int tm  = tid >> 4;
    int bm  = blockIdx.y * 64;
    int bn  = blockIdx.x * 64;

    int arow = tid >> 2;
    int akc  = (tid & 3) << 2;
    int brow = tid >> 4;
    int bcol = (tid & 15) << 2;

    float acc[4][4] = {};

    const float* Aptr = A + (size_t)(bm + arow) * K + akc;
    const float* Wptr = W + (size_t)brow * N + bn + bcol;

    for (int k0 = 0; k0 < K; k0 += 16) {
        float4 av = *reinterpret_cast<const float4*>(Aptr + k0);
        float4 bv = *reinterpret_cast<const float4*>(Wptr + (size_t)k0 * N);
        __syncthreads();
        As[arow][akc + 0] = av.x;
        As[arow][akc + 1] = av.y;
        As[arow][akc + 2] = av.z;
        As[arow][akc + 3] = av.w;
        *reinterpret_cast<float4*>(&Bs[brow][bcol]) = bv;
        __syncthreads();

#pragma unroll
        for (int k = 0; k < 16; ++k) {
            float a[4], b[4];
#pragma unroll
            for (int i = 0; i < 4; ++i) a[i] = As[tm * 4 + i][k];
#pragma unroll
            for (int j = 0; j < 4; ++j) b[j] = Bs[k][tn * 4 + j];
#pragma unroll
            for (int i = 0; i < 4; ++i)
#pragma unroll
                for (int j = 0; j < 4; ++j) acc[i][j] += a[i] * b[j];
        }
    }

    int c = bn + tn * 4;
    float4 bb = *reinterpret_cast<const float4*>(bias + c);
#pragma unroll
    for (int i = 0; i < 4; ++i) {
        int r = bm + tm * 4 + i;
        float4 ov;
        ov.x = acc[i][0] + bb.x;
        ov.y = acc[i][1] + bb.y;
        ov.z = acc[i][2] + bb.z;
        ov.w = acc[i][3] + bb.w;
        if (RELU) {
            ov.x = fmaxf(ov.x, 0.0f); ov.y = fmaxf(ov.y, 0.0f);
            ov.z = fmaxf(ov.z, 0.0f); ov.w = fmaxf(ov.w, 0.0f);
        }
        if (RES) {
            float4 rv = *reinterpret_cast<const float4*>(R + (size_t)r * N + c);
            ov.x += rv.x; ov.y += rv.y; ov.z += rv.z; ov.w += rv.w;
        }
        *reinterpret_cast<float4*>(C + (size_t)r * N + c) = ov;
    }
}

// ---------------------------------------------------------------- Attention
// bf16 MFMA flash attention. qkv layout [B,S,768]: q at col h*64, k at
// 256+h*64, v at 512+h*64. One block = 4 waves handles TWO paired q-tiles
// (pair, 15-pair) of 64 rows each -> uniform 17 kt-iters per block.
// Wave w owns q-stripe rows [16w,16w+16). 16x16x32 bf16 MFMA:
//   A[i][k]: i=l%16, k=8*(l/16)+b   B[k][j]: j=l%16, k=8*(l/16)+b
//   D[i][j]: j=l&15, i=4*(l>>4)+r
// All bf16 LDS tiles are [row][64] with XOR swizzle idx=row*64+(col^((row&7)<<3))
// so stride-128B row reads (ds_read_b128) are <=2-way bank aliased.
__global__ __launch_bounds__(256) void attn_kernel(const float* __restrict__ qkv,
                                                   float* __restrict__ o)
{
    __shared__ short Ks[64 * 64];   // K tile [krow][d]
    __shared__ short Vt[64 * 64];   // V^T tile [d][krow]
    __shared__ short QP[64 * 64];   // Q tile, then reused as P tile [q][k]

    int tid  = threadIdx.x;
    int pair = blockIdx.x, h = blockIdx.y, b = blockIdx.z;
    const float* base = qkv + (size_t)b * 1024 * 768;

    int l   = tid & 63;
    int w   = tid >> 6;            // wave id 0..3
    int lr  = l & 15;              // fragment row/col index
    int lk8 = (l >> 4) * 8;        // fragment k-base
    int r4  = (l >> 4) * 4;        // D-layout row base
    int w16 = w * 16;

    // staging assignment: thread t covers K/V row kr, 16 cols starting c0
    int kr = tid >> 2;
    int c0 = (tid & 3) << 4;

    for (int sel = 0; sel < 2; ++sel) {
        int qt = sel == 0 ? pair : 15 - pair;

        __syncthreads();           // prior tile's QP reads complete
        // ---- stage Q (pre-scaled by 1/sqrt(64)) into QP ----
        {
            const float* qg = base + (size_t)(qt * 64 + kr) * 768 + h * 64;
#pragma unroll
            for (int u = 0; u < 4; ++u) {
                int c = c0 + u * 4;
                float4 qv = *reinterpret_cast<const float4*>(qg + c);
                s16x4 q4;
                q4[0] = f2bf(qv.x * 0.125f);
                q4[1] = f2bf(qv.y * 0.125f);
                q4[2] = f2bf(qv.z * 0.125f);
                q4[3] = f2bf(qv.w * 0.125f);
                *reinterpret_cast<s16x4*>(&QP[kr * 64 + (c ^ ((kr & 7) << 3))]) = q4;
            }
        }
        __syncthreads();

        // ---- hoist Q fragments (constant over kt loop) ----
        s16x8 qf[2];
#pragma unroll
        for (int ks = 0; ks < 2; ++ks) {
            int row = w16 + lr;
            qf[ks] = *reinterpret_cast<const s16x8*>(
                &QP[row * 64 + ((lk8 + 32 * ks) ^ ((row & 7) << 3))]);
        }

        float m[4], lsum[4];
        f32x4 oacc[4];
#pragma unroll
        for (int r = 0; r < 4; ++r) { m[r] = -1e30f; lsum[r] = 0.0f; }
#pragma unroll
        for (int jt = 0; jt < 4; ++jt) oacc[jt] = (f32x4){0.f, 0.f, 0.f, 0.f};

        for (int kt = 0; kt <= qt; ++kt) {
            __syncthreads();       // prior iter's Ks/Vt reads complete
            // ---- stage K and V^T (fp32 -> bf16) ----
            {
                const float* kg = base + (size_t)(kt * 64 + kr) * 768 + 256 + h * 64;
                const float* vg = kg + 256;
#pragma unroll
                for (int u = 0; u < 4; ++u) {
                    int c = c0 + u * 4;
                    float4 kv = *reinterpret_cast<const float4*>(kg + c);
                    float4 vv = *reinterpret_cast<const float4*>(vg + c);
                    s16x4 k4;
                    k4[0] = f2bf(kv.x); k4[1] = f2bf(kv.y);
                    k4[2] = f2bf(kv.z); k4[3] = f2bf(kv.w);
                    *reinterpret_cast<s16x4*>(&Ks[kr * 64 + (c ^ ((kr & 7) << 3))]) = k4;
                    Vt[(c + 0) * 64 + (kr ^ (((c + 0) & 7) << 3))] = f2bf(vv.x);
                    Vt[(c + 1) * 64 + (kr ^ (((c + 1) & 7) << 3))] = f2bf(vv.y);
                    Vt[(c + 2) * 64 + (kr ^ (((c + 2) & 7) << 3))] = f2bf(vv.z);
                    Vt[(c + 3) * 64 + (kr ^ (((c + 3) & 7) << 3))] = f2bf(vv.w);
                }
            }
            __syncthreads();

            // ---- S = Q K^T for this wave's 16-row stripe ----
            f32x4 s[4];
#pragma unroll
            for (int jt = 0; jt < 4; ++jt) s[jt] = (f32x4){0.f, 0.f, 0.f, 0.f};
#pragma unroll
            for (int ks = 0; ks < 2; ++ks) {
#pragma unroll
                for (int jt = 0; jt < 4; ++jt) {
                    int row = jt * 16 + lr;
                    s16x8 kf = *reinterpret_cast<const s16x8*>(
                        &Ks[row * 64 + ((lk8 + 32 * ks) ^ ((row & 7) << 3))]);
                    s[jt] = __builtin_amdgcn_mfma_f32_16x16x32_bf16(qf[ks], kf, s[jt], 0, 0, 0);
                }
            }

            // ---- causal mask on diagonal tile ----
            if (kt == qt) {
#pragma unroll
                for (int jt = 0; jt < 4; ++jt)
#pragma unroll
                    for (int r = 0; r < 4; ++r)
                        if (lr + 16 * jt > w16 + r4 + r) s[jt][r] = -1e30f;
            }

            // ---- online softmax (rows live in 16-lane groups) ----
#pragma unroll
            for (int r = 0; r < 4; ++r) {
                float rm = fmaxf(fmaxf(s[0][r], s[1][r]), fmaxf(s[2][r], s[3][r]));
                rm = fmaxf(rm, __shfl_xor(rm, 1));
                rm = fmaxf(rm, __shfl_xor(rm, 2));
                rm = fmaxf(rm, __shfl_xor(rm, 4));
                rm = fmaxf(rm, __shfl_xor(rm, 8));
                float mn  = fmaxf(m[r], rm);
                float fct = __expf(m[r] - mn);
                m[r] = mn;
                float p0 = __expf(s[0][r] - mn);
                float p1 = __expf(s[1][r] - mn);
                float p2 = __expf(s[2][r] - mn);
                float p3 = __expf(s[3][r] - mn);
                float ps = p0 + p1 + p2 + p3;
                ps += __shfl_xor(ps, 1);
                ps += __shfl_xor(ps, 2);
                ps += __shfl_xor(ps, 4);
                ps += __shfl_xor(ps, 8);
                lsum[r] = lsum[r] * fct + ps;
#pragma unroll
                for (int jt = 0; jt < 4; ++jt) oacc[jt][r] *= fct;
                // write P (bf16) to QP in S-tile coords [q][k]
                int row = w16 + r4 + r;
                int swz = (row & 7) << 3;
                int rb  = row * 64;
                QP[rb + ((lr + 0)  ^ swz)] = f2bf(p0);
                QP[rb + ((lr + 16) ^ swz)] = f2bf(p1);
                QP[rb + ((lr + 32) ^ swz)] = f2bf(p2);
                QP[rb + ((lr + 48) ^ swz)] = f2bf(p3);
            }

            // ---- O += P V  (same-wave LDS write->read: DS pipe is in-order) ----
            int prow = w16 + lr;
            int pswz = (prow & 7) << 3;
#pragma unroll
            for (int ks = 0; ks < 2; ++ks) {
                s16x8 pf = *reinterpret_cast<const s16x8*>(
                    &QP[prow * 64 + ((lk8 + 32 * ks) ^ pswz)]);
#pragma unroll
                for (int jt = 0; jt < 4; ++jt) {
                    int vrow = jt * 16 + lr;
                    s16x8 vf = *reinterpret_cast<const s16x8*>(
                        &Vt[vrow * 64 + ((lk8 + 32 * ks) ^ ((vrow & 7) << 3))]);
                    oacc[jt] = __builtin_amdgcn_mfma_f32_16x16x32_bf16(pf, vf, oacc[jt], 0, 0, 0);
                }
            }
        }

        // ---- finalize: O /= l, store fp32 ----
#pragma unroll
        for (int r = 0; r < 4; ++r) {
            float inv = 1.0f / lsum[r];
            float* orow = o + (size_t)(b * 1024 + qt * 64 + w16 + r4 + r) * 256 + h * 64;
#pragma unroll
            for (int jt = 0; jt < 4; ++jt)
                orow[lr + 16 * jt] = oacc[jt][r] * inv;
        }
    }
}

// ---------------------------------------------------------------- launch
extern "C" void kernel_launch(void* const* d_in, const int* in_sizes, int n_in,
                              void* d_out, int out_size, void* d_ws, size_t ws_size,
                              hipStream_t stream)
{
    const float* x      = (const float*)d_in[0];
    const float* qkv_w  = (const float*)d_in[1];
    const float* qkv_b  = (const float*)d_in[2];
    const float* out_w  = (const float*)d_in[3];
    const float* out_b  = (const float*)d_in[4];
    const float* fc_w   = (const float*)d_in[5];
    const float* fc_b   = (const float*)d_in[6];
    const float* proj_w = (const float*)d_in[7];
    const float* proj_b = (const float*)d_in[8];
    const float* ln1_g  = (const float*)d_in[9];
    const float* ln1_b  = (const float*)d_in[10];
    const float* ln2_g  = (const float*)d_in[11];
    const float* ln2_b  = (const float*)d_in[12];
    float* out = (float*)d_out;

    float* buf0 = (float*)d_ws;            // h / o / h2 : 16384*256 floats
    float* buf1 = buf0 + 4194304;          // qkv / h3   : up to 16384*1024 floats

    dim3 blk(256);

    // 1. h = LN1(x)
    ln_kernel<<<dim3(4096), blk, 0, stream>>>(x, ln1_g, ln1_b, buf0);
    // 2. qkv = h @ qkv_w + qkv_b
    gemm_kernel<0, 0><<<dim3(768 / 64, 256), blk, 0, stream>>>(
        buf0, qkv_w, qkv_b, nullptr, buf1, 768, 256);
    // 3. o = attention(qkv)  — paired causal tiles: 8 pairs x 4 heads x 16 batch
    attn_kernel<<<dim3(8, 4, 16), blk, 0, stream>>>(buf1, buf0);
    // 4. x1 = x + o @ out_w + out_b   -> d_out
    gemm_kernel<0, 1><<<dim3(256 / 64, 256), blk, 0, stream>>>(
        buf0, out_w, out_b, x, out, 256, 256);
    // 5. h2 = LN2(x1)
    ln_kernel<<<dim3(4096), blk, 0, stream>>>(out, ln2_g, ln2_b, buf0);
    // 6. h3 = relu(h2 @ fc_w + fc_b)
    gemm_kernel<1, 0><<<dim3(1024 / 64, 256), blk, 0, stream>>>(
        buf0, fc_w, fc_b, nullptr, buf1, 1024, 256);
    // 7. out = x1 + h3 @ proj_w + proj_b   (in-place residual on d_out)
    gemm_kernel<0, 1><<<dim3(256 / 64, 256), blk, 0, stream>>>(
        buf1, proj_w, proj_b, out, out, 256, 1024);
}

// Round 3
// 154.572 us; speedup vs baseline: 4.7456x; 2.9433x over previous
//
#include <hip/hip_runtime.h>
#include <cstdint>

// Transformer block: B=16, S=1024, E=256, H=4, D=64. fp32 in/out, bf16 compute.
// T = B*S = 16384 tokens.
//
//  0. Wt   = transpose+bf16(weights)    -> ws (per launch, deterministic)
//  1. h    = LN1(x)              bf16   -> bufA [T,256]
//  2. qkv  = h @ qkv_w + qkv_b   bf16   -> bufB [T,768]
//  3. o    = causal_attn(qkv)    bf16   -> bufA [T,256]
//  4. x1   = x + o @ out_w + b   fp32   -> d_out
//  5. h2   = LN2(x1)             bf16   -> bufA [T,256]
//  6. h3   = relu(h2 @ fc_w + b) bf16   -> bufB [T,1024]
//  7. out  = x1 + h3 @ proj_w+b  fp32   -> d_out (in-place residual)

using f32x4 = __attribute__((ext_vector_type(4))) float;
using s16x8 = __attribute__((ext_vector_type(8))) short;
using s16x4 = __attribute__((ext_vector_type(4))) short;

__device__ inline short f2bf(float f) {
    union { float f; unsigned u; } v{f};
    unsigned r = (v.u + 0x7FFFu + ((v.u >> 16) & 1u)) >> 16;   // RNE
    return (short)r;
}

__device__ inline void gload16(const void* g, void* l) {
    __builtin_amdgcn_global_load_lds(
        (const __attribute__((address_space(1))) void*)g,
        (__attribute__((address_space(3))) void*)l, 16, 0, 0);
}

// ------------------------------------------------ weight fp32->bf16 transpose
// Wt[n][k] = bf16(W[k][n]).  Grid: (N/64, K/64), 256 threads.
__global__ __launch_bounds__(256) void wconv_kernel(const float* __restrict__ W,
                                                    short* __restrict__ Wt,
                                                    int K, int N)
{
    __shared__ short T[64][65];
    int tid = threadIdx.x;
    int n0 = blockIdx.x * 64, k0 = blockIdx.y * 64;
    int r  = tid >> 2;
    int c  = (tid & 3) << 4;          // 16 elements

    const float* src = W + (size_t)(k0 + r) * N + n0 + c;
#pragma unroll
    for (int u = 0; u < 4; ++u) {
        float4 v = *reinterpret_cast<const float4*>(src + u * 4);
        T[r][c + u * 4 + 0] = f2bf(v.x);
        T[r][c + u * 4 + 1] = f2bf(v.y);
        T[r][c + u * 4 + 2] = f2bf(v.z);
        T[r][c + u * 4 + 3] = f2bf(v.w);
    }
    __syncthreads();
    s16x8 o0, o1;
#pragma unroll
    for (int j = 0; j < 8; ++j) { o0[j] = T[c + j][r]; o1[j] = T[c + 8 + j][r]; }
    short* dst = Wt + (size_t)(n0 + r) * K + k0 + c;
    *reinterpret_cast<s16x8*>(dst)     = o0;
    *reinterpret_cast<s16x8*>(dst + 8) = o1;
}

// ---------------------------------------------------------------- LayerNorm
// fp32 in -> bf16 out. One wave per 256-float row, 4 rows/block.
__global__ __launch_bounds__(256) void ln_kernel(const float* __restrict__ x,
                                                 const float* __restrict__ gamma,
                                                 const float* __restrict__ beta,
                                                 short* __restrict__ out)
{
    int tid  = threadIdx.x;
    int lane = tid & 63;
    int row  = blockIdx.x * 4 + (tid >> 6);
    const float* xr = x + (size_t)row * 256;
    float4 v = *reinterpret_cast<const float4*>(xr + lane * 4);

    float s = v.x + v.y + v.z + v.w;
#pragma unroll
    for (int o = 32; o >= 1; o >>= 1) s += __shfl_xor(s, o);
    float mu = s * (1.0f / 256.0f);

    float dx = v.x - mu, dy = v.y - mu, dz = v.z - mu, dw = v.w - mu;
    float q = dx * dx + dy * dy + dz * dz + dw * dw;
#pragma unroll
    for (int o = 32; o >= 1; o >>= 1) q += __shfl_xor(q, o);
    float rstd = rsqrtf(q * (1.0f / 256.0f) + 1e-5f);

    float4 gv = *reinterpret_cast<const float4*>(gamma + lane * 4);
    float4 bv = *reinterpret_cast<const float4*>(beta + lane * 4);
    s16x4 ov;
    ov[0] = f2bf(dx * rstd * gv.x + bv.x);
    ov[1] = f2bf(dy * rstd * gv.y + bv.y);
    ov[2] = f2bf(dz * rstd * gv.z + bv.z);
    ov[3] = f2bf(dw * rstd * gv.w + bv.w);
    *reinterpret_cast<s16x4*>(out + (size_t)row * 256 + lane * 4) = ov;
}

// ---------------------------------------------------------------- MFMA GEMM
// C[M,N] = op(A[M,K]bf16 @ Wt[N,K]bf16^T + bias [+ R]) ; 128x128 tile, BK=64.
// 4 waves in 2x2; wave owns 64x64 (4x4 frags of 16x16x32 bf16 MFMA).
// LDS tiles [128][64] bf16, linear for global_load_lds; XOR swizzle
// (col8 ^ ((row&7)<<3) in shorts) applied to GLOBAL source and ds_read addr.
template <int RELU, int RES, int OBF16>
__global__ __launch_bounds__(256) void mgemm_kernel(const short* __restrict__ A,
                                                    const short* __restrict__ Bt,
                                                    const float* __restrict__ bias,
                                                    const float* __restrict__ R,
                                                    void* __restrict__ Cv,
                                                    int N, int K)
{
    __shared__ short As[128 * 64];
    __shared__ short Bs[128 * 64];

    int tid = threadIdx.x;
    int l   = tid & 63;
    int w   = tid >> 6;
    int lr  = l & 15;
    int lk8 = (l >> 4) << 3;       // fragment k-base (shorts)
    int r4  = (l >> 4) << 2;       // D-layout row base
    int wr  = w >> 1, wc = w & 1;  // wave quadrant in 2x2
    int bn  = blockIdx.x * 128, bm = blockIdx.y * 128;

    // staging: lane j covers tile-row w*32 + i*8 + (j>>3), 16B at swizzled col
    int srowoff = (w << 5) + (l >> 3);              // + i*8
    int scolS   = ((l & 7) << 3) ^ ((l >> 3) << 3); // shorts, pre-swizzled source
    const short* pa = A  + (size_t)(bm + srowoff) * K + scolS;
    const short* pb = Bt + (size_t)(bn + srowoff) * K + scolS;
    short* dstA = As + (w << 11);                   // w*2048 shorts (4KB)
    short* dstB = Bs + (w << 11);

    f32x4 acc[4][4];
#pragma unroll
    for (int mi = 0; mi < 4; ++mi)
#pragma unroll
        for (int ni = 0; ni < 4; ++ni) acc[mi][ni] = (f32x4){0.f, 0.f, 0.f, 0.f};

    int swz = (lr & 7) << 3;

    for (int k0 = 0; k0 < K; k0 += 64) {
        __syncthreads();           // prior iter's ds_reads complete
#pragma unroll
        for (int i = 0; i < 4; ++i)
            gload16(pa + (size_t)(i * 8) * K + k0, dstA + (i << 9));
#pragma unroll
        for (int i = 0; i < 4; ++i)
            gload16(pb + (size_t)(i * 8) * K + k0, dstB + (i << 9));
        __syncthreads();           // drains vmcnt + lgkm

#pragma unroll
        for (int ks = 0; ks < 2; ++ks) {
            s16x8 af[4], bf[4];
#pragma unroll
            for (int mi = 0; mi < 4; ++mi) {
                int row = (wr << 6) + (mi << 4) + lr;
                af[mi] = *reinterpret_cast<const s16x8*>(
                    &As[(row << 6) + (((ks << 5) + lk8) ^ swz)]);
            }
#pragma unroll
            for (int ni = 0; ni < 4; ++ni) {
                int row = (wc << 6) + (ni << 4) + lr;
                bf[ni] = *reinterpret_cast<const s16x8*>(
                    &Bs[(row << 6) + (((ks << 5) + lk8) ^ swz)]);
            }
#pragma unroll
            for (int mi = 0; mi < 4; ++mi)
#pragma unroll
                for (int ni = 0; ni < 4; ++ni)
                    acc[mi][ni] = __builtin_amdgcn_mfma_f32_16x16x32_bf16(
                        af[mi], bf[ni], acc[mi][ni], 0, 0, 0);
        }
    }

    // epilogue
    float bv[4];
#pragma unroll
    for (int ni = 0; ni < 4; ++ni)
        bv[ni] = bias[bn + (wc << 6) + (ni << 4) + lr];

#pragma unroll
    for (int mi = 0; mi < 4; ++mi) {
#pragma unroll
        for (int ni = 0; ni < 4; ++ni) {
            int n = bn + (wc << 6) + (ni << 4) + lr;
#pragma unroll
            for (int r = 0; r < 4; ++r) {
                int m = bm + (wr << 6) + (mi << 4) + r4 + r;
                float v = acc[mi][ni][r] + bv[ni];
                if (RELU) v = fmaxf(v, 0.0f);
                if (RES)  v += R[(size_t)m * N + n];
                if (OBF16) ((short*)Cv)[(size_t)m * N + n] = f2bf(v);
                else       ((float*)Cv)[(size_t)m * N + n] = v;
            }
        }
    }
}

// ---------------------------------------------------------------- Attention
// bf16 MFMA flash attention, bf16 in/out. qkv layout [B,S,768] bf16.
// One block = 4 waves handles paired q-tiles (pair, 15-pair); 17 kt-iters.
__global__ __launch_bounds__(256) void attn_kernel(const short* __restrict__ qkv,
                                                   short* __restrict__ o)
{
    __shared__ short Ks[64 * 64];   // K tile [krow][d]
    __shared__ short Vt[64 * 64];   // V^T tile [d][krow]
    __shared__ short QP[64 * 64];   // Q tile, then P tile [q][k]

    int tid  = threadIdx.x;
    int pair = blockIdx.x, h = blockIdx.y, b = blockIdx.z;
    const short* base = qkv + (size_t)b * 1024 * 768;

    int l   = tid & 63;
    int w   = tid >> 6;
    int lr  = l & 15;
    int lk8 = (l >> 4) << 3;
    int r4  = (l >> 4) << 2;
    int w16 = w << 4;

    int kr = tid >> 2;             // staging row 0..63
    int c0 = (tid & 3) << 4;       // staging col (16 shorts)
    int sswz = (kr & 7) << 3;

    for (int sel = 0; sel < 2; ++sel) {
        int qt = sel == 0 ? pair : 15 - pair;

        __syncthreads();           // prior tile's QP reads complete
        {
            const short* qg = base + (size_t)(qt * 64 + kr) * 768 + h * 64 + c0;
            s16x8 q0 = *reinterpret_cast<const s16x8*>(qg);
            s16x8 q1 = *reinterpret_cast<const s16x8*>(qg + 8);
            *reinterpret_cast<s16x8*>(&QP[kr * 64 + (c0 ^ sswz)])       = q0;
            *reinterpret_cast<s16x8*>(&QP[kr * 64 + ((c0 + 8) ^ sswz)]) = q1;
        }
        __syncthreads();

        // hoist Q fragments
        s16x8 qf[2];
#pragma unroll
        for (int ks = 0; ks < 2; ++ks) {
            int row = w16 + lr;
            qf[ks] = *reinterpret_cast<const s16x8*>(
                &QP[row * 64 + ((lk8 + 32 * ks) ^ ((row & 7) << 3))]);
        }

        float m[4], lsum[4];
        f32x4 oacc[4];
#pragma unroll
        for (int r = 0; r < 4; ++r) { m[r] = -1e30f; lsum[r] = 0.0f; }
#pragma unroll
        for (int jt = 0; jt < 4; ++jt) oacc[jt] = (f32x4){0.f, 0.f, 0.f, 0.f};

        for (int kt = 0; kt <= qt; ++kt) {
            __syncthreads();       // prior iter's Ks/Vt reads complete
            {
                const short* kg = base + (size_t)(kt * 64 + kr) * 768 + 256 + h * 64 + c0;
                const short* vg = kg + 256;
                s16x8 k0v = *reinterpret_cast<const s16x8*>(kg);
                s16x8 k1v = *reinterpret_cast<const s16x8*>(kg + 8);
                *reinterpret_cast<s16x8*>(&Ks[kr * 64 + (c0 ^ sswz)])       = k0v;
                *reinterpret_cast<s16x8*>(&Ks[kr * 64 + ((c0 + 8) ^ sswz)]) = k1v;
                s16x8 v0 = *reinterpret_cast<const s16x8*>(vg);
                s16x8 v1 = *reinterpret_cast<const s16x8*>(vg + 8);
#pragma unroll
                for (int e = 0; e < 8; ++e) {
                    int ca = c0 + e, cb = c0 + 8 + e;
                    Vt[ca * 64 + (kr ^ ((ca & 7) << 3))] = v0[e];
                    Vt[cb * 64 + (kr ^ ((cb & 7) << 3))] = v1[e];
                }
            }
            __syncthreads();

            // S = Q K^T (wave's 16-row stripe), then scale by 1/8 in fp32
            f32x4 s[4];
#pragma unroll
            for (int jt = 0; jt < 4; ++jt) s[jt] = (f32x4){0.f, 0.f, 0.f, 0.f};
#pragma unroll
            for (int ks = 0; ks < 2; ++ks) {
#pragma unroll
                for (int jt = 0; jt < 4; ++jt) {
                    int row = jt * 16 + lr;
                    s16x8 kf = *reinterpret_cast<const s16x8*>(
                        &Ks[row * 64 + ((lk8 + 32 * ks) ^ ((row & 7) << 3))]);
                    s[jt] = __builtin_amdgcn_mfma_f32_16x16x32_bf16(qf[ks], kf, s[jt], 0, 0, 0);
                }
            }
#pragma unroll
            for (int jt = 0; jt < 4; ++jt)
#pragma unroll
                for (int r = 0; r < 4; ++r) s[jt][r] *= 0.125f;

            if (kt == qt) {
#pragma unroll
                for (int jt = 0; jt < 4; ++jt)
#pragma unroll
                    for (int r = 0; r < 4; ++r)
                        if (lr + 16 * jt > w16 + r4 + r) s[jt][r] = -1e30f;
            }

            // online softmax (rows in 16-lane groups)
#pragma unroll
            for (int r = 0; r < 4; ++r) {
                float rm = fmaxf(fmaxf(s[0][r], s[1][r]), fmaxf(s[2][r], s[3][r]));
                rm = fmaxf(rm, __shfl_xor(rm, 1));
                rm = fmaxf(rm, __shfl_xor(rm, 2));
                rm = fmaxf(rm, __shfl_xor(rm, 4));
                rm = fmaxf(rm, __shfl_xor(rm, 8));
                float mn  = fmaxf(m[r], rm);
                float fct = __expf(m[r] - mn);
                m[r] = mn;
                float p0 = __expf(s[0][r] - mn);
                float p1 = __expf(s[1][r] - mn);
                float p2 = __expf(s[2][r] - mn);
                float p3 = __expf(s[3][r] - mn);
                float ps = p0 + p1 + p2 + p3;
                ps += __shfl_xor(ps, 1);
                ps += __shfl_xor(ps, 2);
                ps += __shfl_xor(ps, 4);
                ps += __shfl_xor(ps, 8);
                lsum[r] = lsum[r] * fct + ps;
#pragma unroll
                for (int jt = 0; jt < 4; ++jt) oacc[jt][r] *= fct;
                int row = w16 + r4 + r;
                int pswz = (row & 7) << 3;
                int rb = row * 64;
                QP[rb + ((lr + 0)  ^ pswz)] = f2bf(p0);
                QP[rb + ((lr + 16) ^ pswz)] = f2bf(p1);
                QP[rb + ((lr + 32) ^ pswz)] = f2bf(p2);
                QP[rb + ((lr + 48) ^ pswz)] = f2bf(p3);
            }

            // O += P V (same-wave LDS write->read)
            int prow = w16 + lr;
            int pswz2 = (prow & 7) << 3;
#pragma unroll
            for (int ks = 0; ks < 2; ++ks) {
                s16x8 pf = *reinterpret_cast<const s16x8*>(
                    &QP[prow * 64 + ((lk8 + 32 * ks) ^ pswz2)]);
#pragma unroll
                for (int jt = 0; jt < 4; ++jt) {
                    int vrow = jt * 16 + lr;
                    s16x8 vf = *reinterpret_cast<const s16x8*>(
                        &Vt[vrow * 64 + ((lk8 + 32 * ks) ^ ((vrow & 7) << 3))]);
                    oacc[jt] = __builtin_amdgcn_mfma_f32_16x16x32_bf16(pf, vf, oacc[jt], 0, 0, 0);
                }
            }
        }

        // finalize: O /= l, store bf16
#pragma unroll
        for (int r = 0; r < 4; ++r) {
            float inv = 1.0f / lsum[r];
            short* orow = o + (size_t)(b * 1024 + qt * 64 + w16 + r4 + r) * 256 + h * 64;
#pragma unroll
            for (int jt = 0; jt < 4; ++jt)
                orow[lr + 16 * jt] = f2bf(oacc[jt][r] * inv);
        }
    }
}

// ---------------------------------------------------------------- launch
extern "C" void kernel_launch(void* const* d_in, const int* in_sizes, int n_in,
                              void* d_out, int out_size, void* d_ws, size_t ws_size,
                              hipStream_t stream)
{
    const float* x      = (const float*)d_in[0];
    const float* qkv_w  = (const float*)d_in[1];
    const float* qkv_b  = (const float*)d_in[2];
    const float* out_w  = (const float*)d_in[3];
    const float* out_b  = (const float*)d_in[4];
    const float* fc_w   = (const float*)d_in[5];
    const float* fc_b   = (const float*)d_in[6];
    const float* proj_w = (const float*)d_in[7];
    const float* proj_b = (const float*)d_in[8];
    const float* ln1_g  = (const float*)d_in[9];
    const float* ln1_b  = (const float*)d_in[10];
    const float* ln2_g  = (const float*)d_in[11];
    const float* ln2_b  = (const float*)d_in[12];
    float* out = (float*)d_out;

    short* ws = (short*)d_ws;
    short* wt_qkv  = ws;                    // [768][256]  = 196608
    short* wt_out  = ws + 196608;           // [256][256]  = 65536
    short* wt_fc   = ws + 262144;           // [1024][256] = 262144
    short* wt_proj = ws + 524288;           // [256][1024] = 262144
    short* bufA    = ws + 786432;           // [T,256] bf16 (h / o / h2)
    short* bufB    = ws + 4980736;          // [T,768] qkv / [T,1024] h3

    dim3 blk(256);

    // 0. weight convert+transpose
    wconv_kernel<<<dim3(12, 4),  blk, 0, stream>>>(qkv_w,  wt_qkv,  256, 768);
    wconv_kernel<<<dim3(4, 4),   blk, 0, stream>>>(out_w,  wt_out,  256, 256);
    wconv_kernel<<<dim3(16, 4),  blk, 0, stream>>>(fc_w,   wt_fc,   256, 1024);
    wconv_kernel<<<dim3(4, 16),  blk, 0, stream>>>(proj_w, wt_proj, 1024, 256);

    // 1. h = LN1(x)
    ln_kernel<<<dim3(4096), blk, 0, stream>>>(x, ln1_g, ln1_b, bufA);
    // 2. qkv = h @ qkv_w + qkv_b
    mgemm_kernel<0, 0, 1><<<dim3(6, 128), blk, 0, stream>>>(
        bufA, wt_qkv, qkv_b, nullptr, bufB, 768, 256);
    // 3. o = attention(qkv)
    attn_kernel<<<dim3(8, 4, 16), blk, 0, stream>>>(bufB, bufA);
    // 4. x1 = x + o @ out_w + out_b -> d_out (fp32)
    mgemm_kernel<0, 1, 0><<<dim3(2, 128), blk, 0, stream>>>(
        bufA, wt_out, out_b, x, out, 256, 256);
    // 5. h2 = LN2(x1)
    ln_kernel<<<dim3(4096), blk, 0, stream>>>(out, ln2_g, ln2_b, bufA);
    // 6. h3 = relu(h2 @ fc_w + fc_b)
    mgemm_kernel<1, 0, 1><<<dim3(8, 128), blk, 0, stream>>>(
        bufA, wt_fc, fc_b, nullptr, bufB, 1024, 256);
    // 7. out = x1 + h3 @ proj_w + proj_b (in-place residual on d_out)
    mgemm_kernel<0, 1, 0><<<dim3(2, 128), blk, 0, stream>>>(
        bufB, wt_proj, proj_b, out, out, 256, 1024);
}

// Round 4
// 138.520 us; speedup vs baseline: 5.2956x; 1.1159x over previous
//
#include <hip/hip_runtime.h>
#include <cstdint>

// Transformer block: B=16, S=1024, E=256, H=4, D=64. fp32 in/out, bf16 compute.
// T = B*S = 16384 tokens.
//
//  0. Wt    = transpose+bf16(all weights)      -> ws   (one kernel)
//  1. h     = LN1(x)                    bf16   -> bufA
//  2. qkv   = h @ qkv_w + qkv_b         bf16   -> bufB
//  3. o     = causal_attn(qkv)          bf16   -> bufA   (KVBLK=128, XCD-swizzled)
//  4. x1,h2 = fused(x + o@out_w+b, LN2) f32,bf16 -> d_out, bufA
//  5. h3    = relu(h2 @ fc_w + b)       bf16   -> bufB
//  6. out   = x1 + h3 @ proj_w + b      fp32   -> d_out  (BM=64 tiles)

using f32x4 = __attribute__((ext_vector_type(4))) float;
using s16x8 = __attribute__((ext_vector_type(8))) short;
using s16x4 = __attribute__((ext_vector_type(4))) short;

__device__ inline short f2bf(float f) {
    union { float f; unsigned u; } v{f};
    unsigned r = (v.u + 0x7FFFu + ((v.u >> 16) & 1u)) >> 16;   // RNE
    return (short)r;
}

__device__ inline void gload16(const void* g, void* l) {
    __builtin_amdgcn_global_load_lds(
        (const __attribute__((address_space(1))) void*)g,
        (__attribute__((address_space(3))) void*)l, 16, 0, 0);
}

// ------------------------------------------------ weight fp32->bf16 transpose
// All four weights in one launch. Tile ids: [0,48) qkv, [48,64) out,
// [64,128) fc, [128,192) proj.
__global__ __launch_bounds__(256) void wconv_all_kernel(
    const float* __restrict__ qkv_w, const float* __restrict__ out_w,
    const float* __restrict__ fc_w,  const float* __restrict__ proj_w,
    short* __restrict__ wt_qkv, short* __restrict__ wt_out,
    short* __restrict__ wt_fc,  short* __restrict__ wt_proj)
{
    __shared__ short T[64][65];
    int id = blockIdx.x;
    const float* W; short* Wt; int K, N, nt, kt;
    if (id < 48)       { W = qkv_w;  Wt = wt_qkv;  K = 256;  N = 768;  nt = id % 12;        kt = id / 12; }
    else if (id < 64)  { W = out_w;  Wt = wt_out;  K = 256;  N = 256;  nt = (id - 48) & 3;  kt = (id - 48) >> 2; }
    else if (id < 128) { W = fc_w;   Wt = wt_fc;   K = 256;  N = 1024; nt = (id - 64) & 15; kt = (id - 64) >> 4; }
    else               { W = proj_w; Wt = wt_proj; K = 1024; N = 256;  nt = (id - 128) & 3; kt = (id - 128) >> 2; }
    int n0 = nt * 64, k0 = kt * 64;

    int tid = threadIdx.x;
    int r  = tid >> 2;
    int c  = (tid & 3) << 4;

    const float* src = W + (size_t)(k0 + r) * N + n0 + c;
#pragma unroll
    for (int u = 0; u < 4; ++u) {
        float4 v = *reinterpret_cast<const float4*>(src + u * 4);
        T[r][c + u * 4 + 0] = f2bf(v.x);
        T[r][c + u * 4 + 1] = f2bf(v.y);
        T[r][c + u * 4 + 2] = f2bf(v.z);
        T[r][c + u * 4 + 3] = f2bf(v.w);
    }
    __syncthreads();
    s16x8 o0, o1;
#pragma unroll
    for (int j = 0; j < 8; ++j) { o0[j] = T[c + j][r]; o1[j] = T[c + 8 + j][r]; }
    short* dst = Wt + (size_t)(n0 + r) * K + k0 + c;
    *reinterpret_cast<s16x8*>(dst)     = o0;
    *reinterpret_cast<s16x8*>(dst + 8) = o1;
}

// ---------------------------------------------------------------- LayerNorm
__global__ __launch_bounds__(256) void ln_kernel(const float* __restrict__ x,
                                                 const float* __restrict__ gamma,
                                                 const float* __restrict__ beta,
                                                 short* __restrict__ out)
{
    int tid  = threadIdx.x;
    int lane = tid & 63;
    int row  = blockIdx.x * 4 + (tid >> 6);
    const float* xr = x + (size_t)row * 256;
    float4 v = *reinterpret_cast<const float4*>(xr + lane * 4);

    float s = v.x + v.y + v.z + v.w;
#pragma unroll
    for (int o = 32; o >= 1; o >>= 1) s += __shfl_xor(s, o);
    float mu = s * (1.0f / 256.0f);

    float dx = v.x - mu, dy = v.y - mu, dz = v.z - mu, dw = v.w - mu;
    float q = dx * dx + dy * dy + dz * dz + dw * dw;
#pragma unroll
    for (int o = 32; o >= 1; o >>= 1) q += __shfl_xor(q, o);
    float rstd = rsqrtf(q * (1.0f / 256.0f) + 1e-5f);

    float4 gv = *reinterpret_cast<const float4*>(gamma + lane * 4);
    float4 bv = *reinterpret_cast<const float4*>(beta + lane * 4);
    s16x4 ov;
    ov[0] = f2bf(dx * rstd * gv.x + bv.x);
    ov[1] = f2bf(dy * rstd * gv.y + bv.y);
    ov[2] = f2bf(dz * rstd * gv.z + bv.z);
    ov[3] = f2bf(dw * rstd * gv.w + bv.w);
    *reinterpret_cast<s16x4*>(out + (size_t)row * 256 + lane * 4) = ov;
}

// ---------------------------------------------------------------- MFMA GEMM
// C[M,N] = op(A[M,K]bf16 @ Bt[N,K]^T + bias [+ R]). Tile BMx128, BK=64.
// 4 waves 2x2; wave owns (BM/2)x64. Linear LDS dest for global_load_lds;
// XOR swizzle (col8 ^ ((row&7)<<3)) applied to global SOURCE and ds_read.
template <int RELU, int RES, int OBF16, int BM>
__global__ __launch_bounds__(256) void mgemm_kernel(const short* __restrict__ A,
                                                    const short* __restrict__ Bt,
                                                    const float* __restrict__ bias,
                                                    const float* __restrict__ R,
                                                    void* __restrict__ Cv,
                                                    int N, int K)
{
    constexpr int MI = BM / 32;          // m-frags per wave
    __shared__ short As[BM * 64];
    __shared__ short Bs[128 * 64];

    int tid = threadIdx.x;
    int l   = tid & 63;
    int w   = tid >> 6;
    int lr  = l & 15;
    int lk8 = (l >> 4) << 3;
    int r4  = (l >> 4) << 2;
    int wr  = w >> 1, wc = w & 1;
    int bn  = blockIdx.x * 128, bm = blockIdx.y * BM;

    int scolS = ((l & 7) << 3) ^ ((l >> 3) << 3);
    int srowA = w * (BM / 4) + (l >> 3);
    int srowB = (w << 5) + (l >> 3);
    const short* pa = A  + (size_t)(bm + srowA) * K + scolS;
    const short* pb = Bt + (size_t)(bn + srowB) * K + scolS;
    short* dstA = As + w * (BM / 4) * 64;
    short* dstB = Bs + (w << 11);

    f32x4 acc[MI][4];
#pragma unroll
    for (int mi = 0; mi < MI; ++mi)
#pragma unroll
        for (int ni = 0; ni < 4; ++ni) acc[mi][ni] = (f32x4){0.f, 0.f, 0.f, 0.f};

    int swz = (lr & 7) << 3;

    for (int k0 = 0; k0 < K; k0 += 64) {
        __syncthreads();
#pragma unroll
        for (int i = 0; i < BM / 32; ++i)
            gload16(pa + (size_t)(i * 8) * K + k0, dstA + (i << 9));
#pragma unroll
        for (int i = 0; i < 4; ++i)
            gload16(pb + (size_t)(i * 8) * K + k0, dstB + (i << 9));
        __syncthreads();

#pragma unroll
        for (int ks = 0; ks < 2; ++ks) {
            s16x8 af[MI], bf[4];
#pragma unroll
            for (int mi = 0; mi < MI; ++mi) {
                int row = wr * (BM / 2) + (mi << 4) + lr;
                af[mi] = *reinterpret_cast<const s16x8*>(
                    &As[(row << 6) + (((ks << 5) + lk8) ^ swz)]);
            }
#pragma unroll
            for (int ni = 0; ni < 4; ++ni) {
                int row = (wc << 6) + (ni << 4) + lr;
                bf[ni] = *reinterpret_cast<const s16x8*>(
                    &Bs[(row << 6) + (((ks << 5) + lk8) ^ swz)]);
            }
#pragma unroll
            for (int mi = 0; mi < MI; ++mi)
#pragma unroll
                for (int ni = 0; ni < 4; ++ni)
                    acc[mi][ni] = __builtin_amdgcn_mfma_f32_16x16x32_bf16(
                        af[mi], bf[ni], acc[mi][ni], 0, 0, 0);
        }
    }

    float bv[4];
#pragma unroll
    for (int ni = 0; ni < 4; ++ni)
        bv[ni] = bias[bn + (wc << 6) + (ni << 4) + lr];

#pragma unroll
    for (int mi = 0; mi < MI; ++mi) {
#pragma unroll
        for (int ni = 0; ni < 4; ++ni) {
            int n = bn + (wc << 6) + (ni << 4) + lr;
#pragma unroll
            for (int r = 0; r < 4; ++r) {
                int m = bm + wr * (BM / 2) + (mi << 4) + r4 + r;
                float v = acc[mi][ni][r] + bv[ni];
                if (RELU) v = fmaxf(v, 0.0f);
                if (RES)  v += R[(size_t)m * N + n];
                if (OBF16) ((short*)Cv)[(size_t)m * N + n] = f2bf(v);
                else       ((float*)Cv)[(size_t)m * N + n] = v;
            }
        }
    }
}

// ------------------------------------- fused out-proj + residual + LN2
// x1 = x + o @ out_w + out_b (fp32 -> d_out); h2 = LN2(x1) (bf16 -> h2out).
// Tile 64xN(=256); wave w owns rows w*16..w*16+15 across ALL 256 cols, so
// LN is a 16-lane in-register reduction. K=256.
__global__ __launch_bounds__(256) void oproj_ln_kernel(const short* __restrict__ A,
                                                       const short* __restrict__ Bt,
                                                       const float* __restrict__ bias,
                                                       const float* __restrict__ R,
                                                       float* __restrict__ x1,
                                                       short* __restrict__ h2,
                                                       const float* __restrict__ g,
                                                       const float* __restrict__ bb)
{
    __shared__ short As[64 * 64];
    __shared__ short Bs[256 * 64];

    int tid = threadIdx.x;
    int l   = tid & 63;
    int w   = tid >> 6;
    int lr  = l & 15;
    int lk8 = (l >> 4) << 3;
    int r4  = (l >> 4) << 2;
    int bm  = blockIdx.x * 64;

    int scolS = ((l & 7) << 3) ^ ((l >> 3) << 3);
    const short* pa = A  + (size_t)(bm + (w << 4) + (l >> 3)) * 256 + scolS;
    const short* pb = Bt + (size_t)((w << 6) + (l >> 3)) * 256 + scolS;
    short* dstA = As + (w << 10);
    short* dstB = Bs + (w << 12);

    f32x4 acc[16];
#pragma unroll
    for (int ni = 0; ni < 16; ++ni) acc[ni] = (f32x4){0.f, 0.f, 0.f, 0.f};

    int swz = (lr & 7) << 3;

    for (int k0 = 0; k0 < 256; k0 += 64) {
        __syncthreads();
#pragma unroll
        for (int i = 0; i < 2; ++i)
            gload16(pa + (size_t)(i * 8) * 256 + k0, dstA + (i << 9));
#pragma unroll
        for (int i = 0; i < 8; ++i)
            gload16(pb + (size_t)(i * 8) * 256 + k0, dstB + (i << 9));
        __syncthreads();

#pragma unroll
        for (int ks = 0; ks < 2; ++ks) {
            int arow = (w << 4) + lr;
            s16x8 af = *reinterpret_cast<const s16x8*>(
                &As[(arow << 6) + (((ks << 5) + lk8) ^ swz)]);
#pragma unroll
            for (int ni = 0; ni < 16; ++ni) {
                int row = (ni << 4) + lr;
                s16x8 bf = *reinterpret_cast<const s16x8*>(
                    &Bs[(row << 6) + (((ks << 5) + lk8) ^ swz)]);
                acc[ni] = __builtin_amdgcn_mfma_f32_16x16x32_bf16(af, bf, acc[ni], 0, 0, 0);
            }
        }
    }

    // epilogue: bias + residual into acc (= x1 values), then in-register LN
#pragma unroll
    for (int ni = 0; ni < 16; ++ni) {
        int n = (ni << 4) + lr;
        float bvx = bias[n];
#pragma unroll
        for (int r = 0; r < 4; ++r) {
            int m = bm + (w << 4) + r4 + r;
            acc[ni][r] += bvx + R[(size_t)m * 256 + n];
        }
    }
#pragma unroll
    for (int r = 0; r < 4; ++r) {
        float s = 0.0f;
#pragma unroll
        for (int ni = 0; ni < 16; ++ni) s += acc[ni][r];
        s += __shfl_xor(s, 1); s += __shfl_xor(s, 2);
        s += __shfl_xor(s, 4); s += __shfl_xor(s, 8);
        float mu = s * (1.0f / 256.0f);
        float q = 0.0f;
#pragma unroll
        for (int ni = 0; ni < 16; ++ni) {
            float d = acc[ni][r] - mu;
            q += d * d;
        }
        q += __shfl_xor(q, 1); q += __shfl_xor(q, 2);
        q += __shfl_xor(q, 4); q += __shfl_xor(q, 8);
        float rstd = rsqrtf(q * (1.0f / 256.0f) + 1e-5f);

        int m = bm + (w << 4) + r4 + r;
#pragma unroll
        for (int ni = 0; ni < 16; ++ni) {
            int n = (ni << 4) + lr;
            float v = acc[ni][r];
            x1[(size_t)m * 256 + n] = v;
            h2[(size_t)m * 256 + n] = f2bf((v - mu) * rstd * g[n] + bb[n]);
        }
    }
}

// ---------------------------------------------------------------- Attention
// bf16 MFMA flash attention, KVBLK=128, Q-tile=64 (4 waves x 16 rows).
// Block handles paired q-tiles (pair, 15-pair): 9 kv-iters each, balanced.
// Grid 512 linear, XCD-swizzled: id = (bh&7) + 8*(pair + 8*(bh>>3)) so the
// 8 pair-blocks sharing one (b,h)'s K/V land on one XCD's L2.
__global__ __launch_bounds__(256) void attn_kernel(const short* __restrict__ qkv,
                                                   short* __restrict__ o)
{
    __shared__ short Ks[128 * 64];   // [k][d], swz (k&7)<<3
    __shared__ short Vt[2 * 64 * 64];// half h: [d][kk], swz (d&7)<<3
    __shared__ short QP[64 * 128];   // Q in cols 0..63 (stride 128), then P [q][k]

    int bid  = blockIdx.x;
    int slot = bid & 7;
    int kk2  = bid >> 3;
    int pair = kk2 & 7;
    int bh   = slot + ((kk2 >> 3) << 3);
    int b = bh >> 2, h = bh & 3;

    int tid  = threadIdx.x;
    const short* base = qkv + (size_t)b * 1024 * 768;

    int l   = tid & 63;
    int w   = tid >> 6;
    int lr  = l & 15;
    int lk8 = (l >> 4) << 3;
    int r4  = (l >> 4) << 2;
    int w16 = w << 4;

    const float SC = 0.125f * 1.44269504088896f;   // 1/sqrt(D) * log2(e)

    for (int sel = 0; sel < 2; ++sel) {
        int qt = sel == 0 ? pair : 15 - pair;

        __syncthreads();           // prior tile's QP/Ks/Vt reads complete
        // ---- stage Q (rows tid>>2, 16 cols each) ----
        {
            int qr = tid >> 2;
            int c0 = (tid & 3) << 4;
            int sw = (qr & 7) << 3;
            const short* qg = base + (size_t)(qt * 64 + qr) * 768 + h * 64 + c0;
            s16x8 q0 = *reinterpret_cast<const s16x8*>(qg);
            s16x8 q1 = *reinterpret_cast<const s16x8*>(qg + 8);
            *reinterpret_cast<s16x8*>(&QP[qr * 128 + (c0 ^ sw)])       = q0;
            *reinterpret_cast<s16x8*>(&QP[qr * 128 + ((c0 + 8) ^ sw)]) = q1;
        }
        __syncthreads();

        s16x8 qf[2];
#pragma unroll
        for (int ks = 0; ks < 2; ++ks) {
            int row = w16 + lr;
            qf[ks] = *reinterpret_cast<const s16x8*>(
                &QP[row * 128 + ((lk8 + 32 * ks) ^ ((row & 7) << 3))]);
        }

        float m[4], lsum[4];
        f32x4 oacc[4];
#pragma unroll
        for (int r = 0; r < 4; ++r) { m[r] = -1e30f; lsum[r] = 0.0f; }
#pragma unroll
        for (int jt = 0; jt < 4; ++jt) oacc[jt] = (f32x4){0.f, 0.f, 0.f, 0.f};

        int ntile = qt >> 1;       // last kv-tile index
        for (int kt = 0; kt <= ntile; ++kt) {
            __syncthreads();       // prior iter's Ks/Vt reads complete
            // ---- stage K [128][64] and V^T halves [2][64][64] ----
            {
                int c0 = (tid & 3) << 4;
#pragma unroll
                for (int i = 0; i < 2; ++i) {
                    int krow = i * 64 + (tid >> 2);
                    const short* kg = base + (size_t)(kt * 128 + krow) * 768 + 256 + h * 64 + c0;
                    s16x8 k0v = *reinterpret_cast<const s16x8*>(kg);
                    s16x8 k1v = *reinterpret_cast<const s16x8*>(kg + 8);
                    int sw = (krow & 7) << 3;
                    *reinterpret_cast<s16x8*>(&Ks[krow * 64 + (c0 ^ sw)])       = k0v;
                    *reinterpret_cast<s16x8*>(&Ks[krow * 64 + ((c0 + 8) ^ sw)]) = k1v;
                    s16x8 v0 = *reinterpret_cast<const s16x8*>(kg + 256);
                    s16x8 v1 = *reinterpret_cast<const s16x8*>(kg + 264);
                    short* vth = Vt + ((krow >> 6) << 12);
                    int kkl = krow & 63;
#pragma unroll
                    for (int e = 0; e < 8; ++e) {
                        int da = c0 + e, db = c0 + 8 + e;
                        vth[da * 64 + (kkl ^ ((da & 7) << 3))] = v0[e];
                        vth[db * 64 + (kkl ^ ((db & 7) << 3))] = v1[e];
                    }
                }
            }
            __syncthreads();

            // ---- S = Q K^T : 8 k-col tiles x 2 d-slices ----
            f32x4 s[8];
#pragma unroll
            for (int jt = 0; jt < 8; ++jt) s[jt] = (f32x4){0.f, 0.f, 0.f, 0.f};
#pragma unroll
            for (int ks = 0; ks < 2; ++ks) {
#pragma unroll
                for (int jt = 0; jt < 8; ++jt) {
                    int row = jt * 16 + lr;
                    s16x8 kf = *reinterpret_cast<const s16x8*>(
                        &Ks[row * 64 + ((lk8 + 32 * ks) ^ ((lr & 7) << 3))]);
                    s[jt] = __builtin_amdgcn_mfma_f32_16x16x32_bf16(qf[ks], kf, s[jt], 0, 0, 0);
                }
            }
#pragma unroll
            for (int jt = 0; jt < 8; ++jt)
#pragma unroll
                for (int r = 0; r < 4; ++r) s[jt][r] *= SC;

            if (kt == ntile) {     // causal mask (handles odd/even tails)
#pragma unroll
                for (int jt = 0; jt < 8; ++jt)
#pragma unroll
                    for (int r = 0; r < 4; ++r)
                        if (kt * 128 + jt * 16 + lr > qt * 64 + w16 + r4 + r)
                            s[jt][r] = -1e30f;
            }

            // ---- online softmax (base-2) ----
#pragma unroll
            for (int r = 0; r < 4; ++r) {
                float rm = s[0][r];
#pragma unroll
                for (int jt = 1; jt < 8; ++jt) rm = fmaxf(rm, s[jt][r]);
                rm = fmaxf(rm, __shfl_xor(rm, 1));
                rm = fmaxf(rm, __shfl_xor(rm, 2));
                rm = fmaxf(rm, __shfl_xor(rm, 4));
                rm = fmaxf(rm, __shfl_xor(rm, 8));
                float mn  = fmaxf(m[r], rm);
                float fct = exp2f(m[r] - mn);
                m[r] = mn;
                float p[8], ps = 0.0f;
#pragma unroll
                for (int jt = 0; jt < 8; ++jt) { p[jt] = exp2f(s[jt][r] - mn); ps += p[jt]; }
                ps += __shfl_xor(ps, 1);
                ps += __shfl_xor(ps, 2);
                ps += __shfl_xor(ps, 4);
                ps += __shfl_xor(ps, 8);
                lsum[r] = lsum[r] * fct + ps;
#pragma unroll
                for (int jt = 0; jt < 4; ++jt) oacc[jt][r] *= fct;
                int row = w16 + r4 + r;
                int sw  = (row & 15) << 3;
                int rb  = row * 128;
#pragma unroll
                for (int jt = 0; jt < 8; ++jt)
                    QP[rb + ((lr + 16 * jt) ^ sw)] = f2bf(p[jt]);
            }

            // ---- O += P V (P read same-wave) ----
            int prow = w16 + lr;
            int psw  = (prow & 15) << 3;
#pragma unroll
            for (int ks = 0; ks < 4; ++ks) {
                s16x8 pf = *reinterpret_cast<const s16x8*>(
                    &QP[prow * 128 + ((lk8 + 32 * ks) ^ psw)]);
                const short* vth = Vt + ((ks >> 1) << 12);
#pragma unroll
                for (int jt = 0; jt < 4; ++jt) {
                    int vrow = jt * 16 + lr;
                    s16x8 vf = *reinterpret_cast<const s16x8*>(
                        &vth[vrow * 64 + ((((ks & 1) << 5) + lk8) ^ ((lr & 7) << 3))]);
                    oacc[jt] = __builtin_amdgcn_mfma_f32_16x16x32_bf16(pf, vf, oacc[jt], 0, 0, 0);
                }
            }
        }

        // ---- finalize ----
#pragma unroll
        for (int r = 0; r < 4; ++r) {
            float inv = 1.0f / lsum[r];
            short* orow = o + (size_t)(b * 1024 + qt * 64 + w16 + r4 + r) * 256 + h * 64;
#pragma unroll
            for (int jt = 0; jt < 4; ++jt)
                orow[lr + 16 * jt] = f2bf(oacc[jt][r] * inv);
        }
    }
}

// ---------------------------------------------------------------- launch
extern "C" void kernel_launch(void* const* d_in, const int* in_sizes, int n_in,
                              void* d_out, int out_size, void* d_ws, size_t ws_size,
                              hipStream_t stream)
{
    const float* x      = (const float*)d_in[0];
    const float* qkv_w  = (const float*)d_in[1];
    const float* qkv_b  = (const float*)d_in[2];
    const float* out_w  = (const float*)d_in[3];
    const float* out_b  = (const float*)d_in[4];
    const float* fc_w   = (const float*)d_in[5];
    const float* fc_b   = (const float*)d_in[6];
    const float* proj_w = (const float*)d_in[7];
    const float* proj_b = (const float*)d_in[8];
    const float* ln1_g  = (const float*)d_in[9];
    const float* ln1_b  = (const float*)d_in[10];
    const float* ln2_g  = (const float*)d_in[11];
    const float* ln2_b  = (const float*)d_in[12];
    float* out = (float*)d_out;

    short* ws = (short*)d_ws;
    short* wt_qkv  = ws;                    // [768][256]
    short* wt_out  = ws + 196608;           // [256][256]
    short* wt_fc   = ws + 262144;           // [1024][256]
    short* wt_proj = ws + 524288;           // [256][1024]
    short* bufA    = ws + 786432;           // [T,256] bf16 (h / o / h2)
    short* bufB    = ws + 4980736;          // [T,768] qkv / [T,1024] h3

    dim3 blk(256);

    // 0. weight convert+transpose (one kernel)
    wconv_all_kernel<<<dim3(192), blk, 0, stream>>>(
        qkv_w, out_w, fc_w, proj_w, wt_qkv, wt_out, wt_fc, wt_proj);
    // 1. h = LN1(x)
    ln_kernel<<<dim3(4096), blk, 0, stream>>>(x, ln1_g, ln1_b, bufA);
    // 2. qkv = h @ qkv_w + qkv_b
    mgemm_kernel<0, 0, 1, 128><<<dim3(6, 128), blk, 0, stream>>>(
        bufA, wt_qkv, qkv_b, nullptr, bufB, 768, 256);
    // 3. o = attention(qkv)
    attn_kernel<<<dim3(512), blk, 0, stream>>>(bufB, bufA);
    // 4. x1 = x + o@out_w+out_b -> d_out ; h2 = LN2(x1) -> bufA  (fused)
    oproj_ln_kernel<<<dim3(256), blk, 0, stream>>>(
        bufA, wt_out, out_b, x, out, bufA, ln2_g, ln2_b);
    // 5. h3 = relu(h2 @ fc_w + fc_b)
    mgemm_kernel<1, 0, 1, 128><<<dim3(8, 128), blk, 0, stream>>>(
        bufA, wt_fc, fc_b, nullptr, bufB, 1024, 256);
    // 6. out = x1 + h3 @ proj_w + proj_b (in-place residual on d_out)
    mgemm_kernel<0, 1, 0, 64><<<dim3(2, 256), blk, 0, stream>>>(
        bufB, wt_proj, proj_b, out, out, 256, 1024);
}

// Round 5
// 137.623 us; speedup vs baseline: 5.3301x; 1.0065x over previous
//
#include <hip/hip_runtime.h>
#include <cstdint>

// Transformer block: B=16, S=1024, E=256, H=4, D=64. fp32 in/out, bf16 compute.
// T = B*S = 16384 tokens.
//
//  0. Wt    = transpose+bf16(all weights)      -> ws   (one kernel)
//  1. h     = LN1(x)                    bf16   -> bufA
//  2. qkv   = h @ qkv_w + qkv_b         bf16   -> bufB
//  3. o     = causal_attn(qkv)          bf16   -> bufA   (swapped-QK^T, reg softmax)
//  4. x1,h2 = fused(x + o@out_w+b, LN2) f32,bf16 -> d_out, bufA
//  5. h3    = relu(h2 @ fc_w + b)       bf16   -> bufB
//  6. out   = x1 + h3 @ proj_w + b      fp32   -> d_out  (BM=64 tiles)

using f32x4 = __attribute__((ext_vector_type(4))) float;
using s16x8 = __attribute__((ext_vector_type(8))) short;
using s16x4 = __attribute__((ext_vector_type(4))) short;

__device__ inline short f2bf(float f) {
    union { float f; unsigned u; } v{f};
    unsigned r = (v.u + 0x7FFFu + ((v.u >> 16) & 1u)) >> 16;   // RNE
    return (short)r;
}

__device__ inline int cvt_pk_bf16(float lo, float hi) {
    int d;
    asm("v_cvt_pk_bf16_f32 %0, %1, %2" : "=v"(d) : "v"(lo), "v"(hi));
    return d;
}
// After: a = {a_lo32, b_lo32}, b = {a_hi32, b_hi32}
__device__ inline void swap32(int& a, int& b) {
    asm("v_permlane32_swap_b32 %0, %1" : "+v"(a), "+v"(b));
}
// After: a = {a_g0, b_g0, a_g2, b_g2}, b = {a_g1, b_g1, a_g3, b_g3} (16-lane groups)
__device__ inline void swap16(int& a, int& b) {
    asm("v_permlane16_swap_b32 %0, %1" : "+v"(a), "+v"(b));
}

__device__ inline void gload16(const void* g, void* l) {
    __builtin_amdgcn_global_load_lds(
        (const __attribute__((address_space(1))) void*)g,
        (__attribute__((address_space(3))) void*)l, 16, 0, 0);
}

// ------------------------------------------------ weight fp32->bf16 transpose
__global__ __launch_bounds__(256) void wconv_all_kernel(
    const float* __restrict__ qkv_w, const float* __restrict__ out_w,
    const float* __restrict__ fc_w,  const float* __restrict__ proj_w,
    short* __restrict__ wt_qkv, short* __restrict__ wt_out,
    short* __restrict__ wt_fc,  short* __restrict__ wt_proj)
{
    __shared__ short T[64][65];
    int id = blockIdx.x;
    const float* W; short* Wt; int K, N, nt, kt;
    if (id < 48)       { W = qkv_w;  Wt = wt_qkv;  K = 256;  N = 768;  nt = id % 12;        kt = id / 12; }
    else if (id < 64)  { W = out_w;  Wt = wt_out;  K = 256;  N = 256;  nt = (id - 48) & 3;  kt = (id - 48) >> 2; }
    else if (id < 128) { W = fc_w;   Wt = wt_fc;   K = 256;  N = 1024; nt = (id - 64) & 15; kt = (id - 64) >> 4; }
    else               { W = proj_w; Wt = wt_proj; K = 1024; N = 256;  nt = (id - 128) & 3; kt = (id - 128) >> 2; }
    int n0 = nt * 64, k0 = kt * 64;

    int tid = threadIdx.x;
    int r  = tid >> 2;
    int c  = (tid & 3) << 4;

    const float* src = W + (size_t)(k0 + r) * N + n0 + c;
#pragma unroll
    for (int u = 0; u < 4; ++u) {
        float4 v = *reinterpret_cast<const float4*>(src + u * 4);
        T[r][c + u * 4 + 0] = f2bf(v.x);
        T[r][c + u * 4 + 1] = f2bf(v.y);
        T[r][c + u * 4 + 2] = f2bf(v.z);
        T[r][c + u * 4 + 3] = f2bf(v.w);
    }
    __syncthreads();
    s16x8 o0, o1;
#pragma unroll
    for (int j = 0; j < 8; ++j) { o0[j] = T[c + j][r]; o1[j] = T[c + 8 + j][r]; }
    short* dst = Wt + (size_t)(n0 + r) * K + k0 + c;
    *reinterpret_cast<s16x8*>(dst)     = o0;
    *reinterpret_cast<s16x8*>(dst + 8) = o1;
}

// ---------------------------------------------------------------- LayerNorm
__global__ __launch_bounds__(256) void ln_kernel(const float* __restrict__ x,
                                                 const float* __restrict__ gamma,
                                                 const float* __restrict__ beta,
                                                 short* __restrict__ out)
{
    int tid  = threadIdx.x;
    int lane = tid & 63;
    int row  = blockIdx.x * 4 + (tid >> 6);
    const float* xr = x + (size_t)row * 256;
    float4 v = *reinterpret_cast<const float4*>(xr + lane * 4);

    float s = v.x + v.y + v.z + v.w;
#pragma unroll
    for (int o = 32; o >= 1; o >>= 1) s += __shfl_xor(s, o);
    float mu = s * (1.0f / 256.0f);

    float dx = v.x - mu, dy = v.y - mu, dz = v.z - mu, dw = v.w - mu;
    float q = dx * dx + dy * dy + dz * dz + dw * dw;
#pragma unroll
    for (int o = 32; o >= 1; o >>= 1) q += __shfl_xor(q, o);
    float rstd = rsqrtf(q * (1.0f / 256.0f) + 1e-5f);

    float4 gv = *reinterpret_cast<const float4*>(gamma + lane * 4);
    float4 bv = *reinterpret_cast<const float4*>(beta + lane * 4);
    s16x4 ov;
    ov[0] = f2bf(dx * rstd * gv.x + bv.x);
    ov[1] = f2bf(dy * rstd * gv.y + bv.y);
    ov[2] = f2bf(dz * rstd * gv.z + bv.z);
    ov[3] = f2bf(dw * rstd * gv.w + bv.w);
    *reinterpret_cast<s16x4*>(out + (size_t)row * 256 + lane * 4) = ov;
}

// ---------------------------------------------------------------- MFMA GEMM
template <int RELU, int RES, int OBF16, int BM>
__global__ __launch_bounds__(256) void mgemm_kernel(const short* __restrict__ A,
                                                    const short* __restrict__ Bt,
                                                    const float* __restrict__ bias,
                                                    const float* __restrict__ R,
                                                    void* __restrict__ Cv,
                                                    int N, int K)
{
    constexpr int MI = BM / 32;
    __shared__ short As[BM * 64];
    __shared__ short Bs[128 * 64];

    int tid = threadIdx.x;
    int l   = tid & 63;
    int w   = tid >> 6;
    int lr  = l & 15;
    int lk8 = (l >> 4) << 3;
    int r4  = (l >> 4) << 2;
    int wr  = w >> 1, wc = w & 1;
    int bn  = blockIdx.x * 128, bm = blockIdx.y * BM;

    int scolS = ((l & 7) << 3) ^ ((l >> 3) << 3);
    int srowA = w * (BM / 4) + (l >> 3);
    int srowB = (w << 5) + (l >> 3);
    const short* pa = A  + (size_t)(bm + srowA) * K + scolS;
    const short* pb = Bt + (size_t)(bn + srowB) * K + scolS;
    short* dstA = As + w * (BM / 4) * 64;
    short* dstB = Bs + (w << 11);

    f32x4 acc[MI][4];
#pragma unroll
    for (int mi = 0; mi < MI; ++mi)
#pragma unroll
        for (int ni = 0; ni < 4; ++ni) acc[mi][ni] = (f32x4){0.f, 0.f, 0.f, 0.f};

    int swz = (lr & 7) << 3;

    for (int k0 = 0; k0 < K; k0 += 64) {
        __syncthreads();
#pragma unroll
        for (int i = 0; i < BM / 32; ++i)
            gload16(pa + (size_t)(i * 8) * K + k0, dstA + (i << 9));
#pragma unroll
        for (int i = 0; i < 4; ++i)
            gload16(pb + (size_t)(i * 8) * K + k0, dstB + (i << 9));
        __syncthreads();

#pragma unroll
        for (int ks = 0; ks < 2; ++ks) {
            s16x8 af[MI], bf[4];
#pragma unroll
            for (int mi = 0; mi < MI; ++mi) {
                int row = wr * (BM / 2) + (mi << 4) + lr;
                af[mi] = *reinterpret_cast<const s16x8*>(
                    &As[(row << 6) + (((ks << 5) + lk8) ^ swz)]);
            }
#pragma unroll
            for (int ni = 0; ni < 4; ++ni) {
                int row = (wc << 6) + (ni << 4) + lr;
                bf[ni] = *reinterpret_cast<const s16x8*>(
                    &Bs[(row << 6) + (((ks << 5) + lk8) ^ swz)]);
            }
#pragma unroll
            for (int mi = 0; mi < MI; ++mi)
#pragma unroll
                for (int ni = 0; ni < 4; ++ni)
                    acc[mi][ni] = __builtin_amdgcn_mfma_f32_16x16x32_bf16(
                        af[mi], bf[ni], acc[mi][ni], 0, 0, 0);
        }
    }

    float bv[4];
#pragma unroll
    for (int ni = 0; ni < 4; ++ni)
        bv[ni] = bias[bn + (wc << 6) + (ni << 4) + lr];

#pragma unroll
    for (int mi = 0; mi < MI; ++mi) {
#pragma unroll
        for (int ni = 0; ni < 4; ++ni) {
            int n = bn + (wc << 6) + (ni << 4) + lr;
#pragma unroll
            for (int r = 0; r < 4; ++r) {
                int m = bm + wr * (BM / 2) + (mi << 4) + r4 + r;
                float v = acc[mi][ni][r] + bv[ni];
                if (RELU) v = fmaxf(v, 0.0f);
                if (RES)  v += R[(size_t)m * N + n];
                if (OBF16) ((short*)Cv)[(size_t)m * N + n] = f2bf(v);
                else       ((float*)Cv)[(size_t)m * N + n] = v;
            }
        }
    }
}

// ------------------------------------- fused out-proj + residual + LN2
__global__ __launch_bounds__(256) void oproj_ln_kernel(const short* __restrict__ A,
                                                       const short* __restrict__ Bt,
                                                       const float* __restrict__ bias,
                                                       const float* __restrict__ R,
                                                       float* __restrict__ x1,
                                                       short* __restrict__ h2,
                                                       const float* __restrict__ g,
                                                       const float* __restrict__ bb)
{
    __shared__ short As[64 * 64];
    __shared__ short Bs[256 * 64];

    int tid = threadIdx.x;
    int l   = tid & 63;
    int w   = tid >> 6;
    int lr  = l & 15;
    int lk8 = (l >> 4) << 3;
    int r4  = (l >> 4) << 2;
    int bm  = blockIdx.x * 64;

    int scolS = ((l & 7) << 3) ^ ((l >> 3) << 3);
    const short* pa = A  + (size_t)(bm + (w << 4) + (l >> 3)) * 256 + scolS;
    const short* pb = Bt + (size_t)((w << 6) + (l >> 3)) * 256 + scolS;
    short* dstA = As + (w << 10);
    short* dstB = Bs + (w << 12);

    f32x4 acc[16];
#pragma unroll
    for (int ni = 0; ni < 16; ++ni) acc[ni] = (f32x4){0.f, 0.f, 0.f, 0.f};

    int swz = (lr & 7) << 3;

    for (int k0 = 0; k0 < 256; k0 += 64) {
        __syncthreads();
#pragma unroll
        for (int i = 0; i < 2; ++i)
            gload16(pa + (size_t)(i * 8) * 256 + k0, dstA + (i << 9));
#pragma unroll
        for (int i = 0; i < 8; ++i)
            gload16(pb + (size_t)(i * 8) * 256 + k0, dstB + (i << 9));
        __syncthreads();

#pragma unroll
        for (int ks = 0; ks < 2; ++ks) {
            int arow = (w << 4) + lr;
            s16x8 af = *reinterpret_cast<const s16x8*>(
                &As[(arow << 6) + (((ks << 5) + lk8) ^ swz)]);
#pragma unroll
            for (int ni = 0; ni < 16; ++ni) {
                int row = (ni << 4) + lr;
                s16x8 bf = *reinterpret_cast<const s16x8*>(
                    &Bs[(row << 6) + (((ks << 5) + lk8) ^ swz)]);
                acc[ni] = __builtin_amdgcn_mfma_f32_16x16x32_bf16(af, bf, acc[ni], 0, 0, 0);
            }
        }
    }

#pragma unroll
    for (int ni = 0; ni < 16; ++ni) {
        int n = (ni << 4) + lr;
        float bvx = bias[n];
#pragma unroll
        for (int r = 0; r < 4; ++r) {
            int m = bm + (w << 4) + r4 + r;
            acc[ni][r] += bvx + R[(size_t)m * 256 + n];
        }
    }
#pragma unroll
    for (int r = 0; r < 4; ++r) {
        float s = 0.0f;
#pragma unroll
        for (int ni = 0; ni < 16; ++ni) s += acc[ni][r];
        s += __shfl_xor(s, 1); s += __shfl_xor(s, 2);
        s += __shfl_xor(s, 4); s += __shfl_xor(s, 8);
        float mu = s * (1.0f / 256.0f);
        float q = 0.0f;
#pragma unroll
        for (int ni = 0; ni < 16; ++ni) {
            float d = acc[ni][r] - mu;
            q += d * d;
        }
        q += __shfl_xor(q, 1); q += __shfl_xor(q, 2);
        q += __shfl_xor(q, 4); q += __shfl_xor(q, 8);
        float rstd = rsqrtf(q * (1.0f / 256.0f) + 1e-5f);

        int m = bm + (w << 4) + r4 + r;
#pragma unroll
        for (int ni = 0; ni < 16; ++ni) {
            int n = (ni << 4) + lr;
            float v = acc[ni][r];
            x1[(size_t)m * 256 + n] = v;
            h2[(size_t)m * 256 + n] = f2bf((v - mu) * rstd * g[n] + bb[n]);
        }
    }
}

// ---------------------------------------------------------------- Attention
// Swapped-QK^T flash attention (T12 structure). One block = one 64-row q-tile
// (4 waves x 16 q). KVBLK=128. S^T = mfma(A=K, B=Q): lane holds q = lane&15,
// k = 16*jt + 4*(lane>>4) + r in registers -> softmax is in-lane + 2 shfls.
// P packed to bf16 via v_cvt_pk_bf16_f32, redistributed to PV A-fragments
// via v_permlane32_swap + v_permlane16_swap (no LDS for P).
// Grid 1024 = 8 XCD-slots x (16 qt x 8 bh-groups); all qt of a (b,h) share XCD.
__global__ __launch_bounds__(256, 4) void attn_kernel(const short* __restrict__ qkv,
                                                      short* __restrict__ o)
{
    __shared__ short Qs[64 * 64];    // [q][d], swz (q&7)<<3
    __shared__ short Ks[128 * 64];   // [k][d], swz (k&7)<<3
    __shared__ short Vt[2 * 64 * 64];// per 64-k half: [d][kk], swz (d&7)<<3

    int bid  = blockIdx.x;
    int xcd  = bid & 7;
    int rest = bid >> 3;             // 0..127
    int qt   = rest & 15;
    int bh   = ((rest >> 4) << 3) | xcd;
    int b = bh >> 2, h = bh & 3;

    int tid = threadIdx.x;
    const short* base = qkv + (size_t)b * 1024 * 768;

    int l   = tid & 63;
    int w   = tid >> 6;
    int lr  = l & 15;                // q-column owned (softmax) / d-col (PV out)
    int g   = l >> 4;                // 16-lane group 0..3
    int lk8 = g << 3;
    int w16 = w << 4;
    int qglob = qt * 64 + w16 + lr;  // this lane's q row (softmax coords)

    const float SC = 0.125f * 1.44269504088896f;   // 1/sqrt(D) * log2(e)

    // ---- stage Q tile [64][64] ----
    {
        int qr = tid >> 2;
        int c0 = (tid & 3) << 4;
        int sw = (qr & 7) << 3;
        const short* qg = base + (size_t)(qt * 64 + qr) * 768 + h * 64 + c0;
        s16x8 q0 = *reinterpret_cast<const s16x8*>(qg);
        s16x8 q1 = *reinterpret_cast<const s16x8*>(qg + 8);
        *reinterpret_cast<s16x8*>(&Qs[qr * 64 + (c0 ^ sw)])       = q0;
        *reinterpret_cast<s16x8*>(&Qs[qr * 64 + ((c0 + 8) ^ sw)]) = q1;
    }
    __syncthreads();

    // Q fragments (B-operand): lane j = lr = q, k-dim = d
    s16x8 qf[2];
#pragma unroll
    for (int ks = 0; ks < 2; ++ks) {
        int row = w16 + lr;
        qf[ks] = *reinterpret_cast<const s16x8*>(
            &Qs[row * 64 + ((32 * ks + lk8) ^ ((lr & 7) << 3))]);
    }

    float m = -1e30f, lsum = 0.0f;   // stats for q = qglob (replicated over g)
    f32x4 oacc[4];                   // O[q=4g+r][d=16dt+lr]
#pragma unroll
    for (int dt = 0; dt < 4; ++dt) oacc[dt] = (f32x4){0.f, 0.f, 0.f, 0.f};

    int ntile = qt >> 1;
    for (int kt = 0; kt <= ntile; ++kt) {
        __syncthreads();             // prior iter's Ks/Vt reads complete
        // ---- stage K [128][64] and V^T halves [2][64][64] ----
        {
            int c0 = (tid & 3) << 4;
#pragma unroll
            for (int i = 0; i < 2; ++i) {
                int krow = i * 64 + (tid >> 2);
                const short* kg = base + (size_t)(kt * 128 + krow) * 768 + 256 + h * 64 + c0;
                s16x8 k0v = *reinterpret_cast<const s16x8*>(kg);
                s16x8 k1v = *reinterpret_cast<const s16x8*>(kg + 8);
                int sw = (krow & 7) << 3;
                *reinterpret_cast<s16x8*>(&Ks[krow * 64 + (c0 ^ sw)])       = k0v;
                *reinterpret_cast<s16x8*>(&Ks[krow * 64 + ((c0 + 8) ^ sw)]) = k1v;
                s16x8 v0 = *reinterpret_cast<const s16x8*>(kg + 256);
                s16x8 v1 = *reinterpret_cast<const s16x8*>(kg + 264);
                short* vth = Vt + ((krow >> 6) << 12);
                int kkl = krow & 63;
#pragma unroll
                for (int e = 0; e < 8; ++e) {
                    int da = c0 + e, db = c0 + 8 + e;
                    vth[da * 64 + (kkl ^ ((da & 7) << 3))] = v0[e];
                    vth[db * 64 + (kkl ^ ((db & 7) << 3))] = v1[e];
                }
            }
        }
        __syncthreads();

        // ---- S^T = K Q^T : 8 k-tiles (16 k each) x 2 d-slices ----
        f32x4 s[8];
#pragma unroll
        for (int jt = 0; jt < 8; ++jt) s[jt] = (f32x4){0.f, 0.f, 0.f, 0.f};
#pragma unroll
        for (int ks = 0; ks < 2; ++ks) {
#pragma unroll
            for (int jt = 0; jt < 8; ++jt) {
                int row = jt * 16 + lr;
                s16x8 kf = *reinterpret_cast<const s16x8*>(
                    &Ks[row * 64 + ((32 * ks + lk8) ^ ((lr & 7) << 3))]);
                s[jt] = __builtin_amdgcn_mfma_f32_16x16x32_bf16(kf, qf[ks], s[jt], 0, 0, 0);
            }
        }
        // scale (base-2 domain)
#pragma unroll
        for (int jt = 0; jt < 8; ++jt)
#pragma unroll
            for (int r = 0; r < 4; ++r) s[jt][r] *= SC;

        if (kt == ntile) {           // causal mask, wave-uniform branch
#pragma unroll
            for (int jt = 0; jt < 8; ++jt) {
                int kb = kt * 128 + jt * 16 + 4 * g;
#pragma unroll
                for (int r = 0; r < 4; ++r)
                    if (kb + r > qglob) s[jt][r] = -1e30f;
            }
        }

        // ---- in-register online softmax (lane owns q = qglob) ----
        float rm = fmaxf(fmaxf(s[0][0], s[0][1]), fmaxf(s[0][2], s[0][3]));
#pragma unroll
        for (int jt = 1; jt < 8; ++jt) {
            float t = fmaxf(fmaxf(s[jt][0], s[jt][1]), fmaxf(s[jt][2], s[jt][3]));
            rm = fmaxf(rm, t);
        }
        rm = fmaxf(rm, __shfl_xor(rm, 16));
        rm = fmaxf(rm, __shfl_xor(rm, 32));
        float mn  = fmaxf(m, rm);
        float fct = exp2f(m - mn);
        m = mn;
        float ps = 0.0f;
#pragma unroll
        for (int jt = 0; jt < 8; ++jt) {
#pragma unroll
            for (int r = 0; r < 4; ++r) {
                float p = exp2f(s[jt][r] - mn);
                s[jt][r] = p;
                ps += p;
            }
        }
        ps += __shfl_xor(ps, 16);
        ps += __shfl_xor(ps, 32);
        lsum = lsum * fct + ps;

        // pack P to bf16 pairs: c[jt][h] = k-pair {16jt+4g+2h, +1}
        int cpk[8][2];
#pragma unroll
        for (int jt = 0; jt < 8; ++jt) {
            cpk[jt][0] = cvt_pk_bf16(s[jt][0], s[jt][1]);
            cpk[jt][1] = cvt_pk_bf16(s[jt][2], s[jt][3]);
        }

        // rescale O: factor for q = 4g+r gathered from lane 4g+r
#pragma unroll
        for (int r = 0; r < 4; ++r) {
            float f4 = __shfl(fct, 4 * g + r);
#pragma unroll
            for (int dt = 0; dt < 4; ++dt) oacc[dt][r] *= f4;
        }

        // ---- O += P V : per 32-k slice, gather A-frag via permlane swaps ----
#pragma unroll
        for (int ks = 0; ks < 4; ++ks) {
            int a0 = cpk[2 * ks][0],     a1 = cpk[2 * ks][1];
            int b0 = cpk[2 * ks + 1][0], b1 = cpk[2 * ks + 1][1];
            swap32(a0, b0); swap32(a1, b1);
            swap16(a0, b0); swap16(a1, b1);
            union { int i[4]; s16x8 v; } fr;
            fr.i[0] = a0; fr.i[1] = a1; fr.i[2] = b0; fr.i[3] = b1;
            const short* vth = Vt + ((ks >> 1) << 12);
#pragma unroll
            for (int dt = 0; dt < 4; ++dt) {
                int vrow = dt * 16 + lr;
                s16x8 vf = *reinterpret_cast<const s16x8*>(
                    &vth[vrow * 64 + ((((ks & 1) << 5) + lk8) ^ ((lr & 7) << 3))]);
                oacc[dt] = __builtin_amdgcn_mfma_f32_16x16x32_bf16(fr.v, vf, oacc[dt], 0, 0, 0);
            }
        }
    }

    // ---- finalize: O[q=4g+r][d=16dt+lr] /= lsum[q], store bf16 ----
#pragma unroll
    for (int r = 0; r < 4; ++r) {
        float lv  = __shfl(lsum, 4 * g + r);
        float inv = 1.0f / lv;
        short* orow = o + (size_t)(b * 1024 + qt * 64 + w16 + 4 * g + r) * 256 + h * 64;
#pragma unroll
        for (int dt = 0; dt < 4; ++dt)
            orow[dt * 16 + lr] = f2bf(oacc[dt][r] * inv);
    }
}

// ---------------------------------------------------------------- launch
extern "C" void kernel_launch(void* const* d_in, const int* in_sizes, int n_in,
                              void* d_out, int out_size, void* d_ws, size_t ws_size,
                              hipStream_t stream)
{
    const float* x      = (const float*)d_in[0];
    const float* qkv_w  = (const float*)d_in[1];
    const float* qkv_b  = (const float*)d_in[2];
    const float* out_w  = (const float*)d_in[3];
    const float* out_b  = (const float*)d_in[4];
    const float* fc_w   = (const float*)d_in[5];
    const float* fc_b   = (const float*)d_in[6];
    const float* proj_w = (const float*)d_in[7];
    const float* proj_b = (const float*)d_in[8];
    const float* ln1_g  = (const float*)d_in[9];
    const float* ln1_b  = (const float*)d_in[10];
    const float* ln2_g  = (const float*)d_in[11];
    const float* ln2_b  = (const float*)d_in[12];
    float* out = (float*)d_out;

    short* ws = (short*)d_ws;
    short* wt_qkv  = ws;                    // [768][256]
    short* wt_out  = ws + 196608;           // [256][256]
    short* wt_fc   = ws + 262144;           // [1024][256]
    short* wt_proj = ws + 524288;           // [256][1024]
    short* bufA    = ws + 786432;           // [T,256] bf16 (h / o / h2)
    short* bufB    = ws + 4980736;          // [T,768] qkv / [T,1024] h3

    dim3 blk(256);

    // 0. weight convert+transpose
    wconv_all_kernel<<<dim3(192), blk, 0, stream>>>(
        qkv_w, out_w, fc_w, proj_w, wt_qkv, wt_out, wt_fc, wt_proj);
    // 1. h = LN1(x)
    ln_kernel<<<dim3(4096), blk, 0, stream>>>(x, ln1_g, ln1_b, bufA);
    // 2. qkv = h @ qkv_w + qkv_b
    mgemm_kernel<0, 0, 1, 128><<<dim3(6, 128), blk, 0, stream>>>(
        bufA, wt_qkv, qkv_b, nullptr, bufB, 768, 256);
    // 3. o = attention(qkv)
    attn_kernel<<<dim3(1024), blk, 0, stream>>>(bufB, bufA);
    // 4. x1 = x + o@out_w+out_b -> d_out ; h2 = LN2(x1) -> bufA  (fused)
    oproj_ln_kernel<<<dim3(256), blk, 0, stream>>>(
        bufA, wt_out, out_b, x, out, bufA, ln2_g, ln2_b);
    // 5. h3 = relu(h2 @ fc_w + fc_b)
    mgemm_kernel<1, 0, 1, 128><<<dim3(8, 128), blk, 0, stream>>>(
        bufA, wt_fc, fc_b, nullptr, bufB, 1024, 256);
    // 6. out = x1 + h3 @ proj_w + proj_b (in-place residual on d_out)
    mgemm_kernel<0, 1, 0, 64><<<dim3(2, 256), blk, 0, stream>>>(
        bufB, wt_proj, proj_b, out, out, 256, 1024);
}

// Round 6
// 125.364 us; speedup vs baseline: 5.8513x; 1.0978x over previous
//
#include <hip/hip_runtime.h>
#include <cstdint>

// Transformer block: B=16, S=1024, E=256, H=4, D=64. fp32 in/out, bf16 compute.
// T = B*S = 16384 tokens.
//
//  0. Wt    = transpose+bf16(all weights)      -> ws
//  1. h     = LN1(x)                    bf16   -> bufA
//  2. qkv   = h @ qkv_w + qkv_b         bf16   -> qk_buf [T,512] + vt_buf [BH,64,1024]
//  3. o     = causal_attn(qk, vt)       bf16   -> bufA   (2-phase dbuf, reg softmax)
//  4. x1,h2 = fused(x + o@out_w+b, LN2) f32,bf16 -> d_out, bufA
//  5. h3    = relu(h2 @ fc_w + b)       bf16   -> bufB (overlays qk/vt)
//  6. out   = x1 + h3 @ proj_w + b      fp32   -> d_out

using f32x4 = __attribute__((ext_vector_type(4))) float;
using s16x8 = __attribute__((ext_vector_type(8))) short;
using s16x4 = __attribute__((ext_vector_type(4))) short;

__device__ inline short f2bf(float f) {
    union { float f; unsigned u; } v{f};
    unsigned r = (v.u + 0x7FFFu + ((v.u >> 16) & 1u)) >> 16;   // RNE
    return (short)r;
}

__device__ inline int cvt_pk_bf16(float lo, float hi) {
    int d;
    asm("v_cvt_pk_bf16_f32 %0, %1, %2" : "=v"(d) : "v"(lo), "v"(hi));
    return d;
}
__device__ inline void swap32(int& a, int& b) {
    asm("v_permlane32_swap_b32 %0, %1" : "+v"(a), "+v"(b));
}
__device__ inline void swap16(int& a, int& b) {
    asm("v_permlane16_swap_b32 %0, %1" : "+v"(a), "+v"(b));
}

__device__ inline void gload16(const void* g, void* l) {
    __builtin_amdgcn_global_load_lds(
        (const __attribute__((address_space(1))) void*)g,
        (__attribute__((address_space(3))) void*)l, 16, 0, 0);
}

// ------------------------------------------------ weight fp32->bf16 transpose
__global__ __launch_bounds__(256) void wconv_all_kernel(
    const float* __restrict__ qkv_w, const float* __restrict__ out_w,
    const float* __restrict__ fc_w,  const float* __restrict__ proj_w,
    short* __restrict__ wt_qkv, short* __restrict__ wt_out,
    short* __restrict__ wt_fc,  short* __restrict__ wt_proj)
{
    __shared__ short T[64][65];
    int id = blockIdx.x;
    const float* W; short* Wt; int K, N, nt, kt;
    if (id < 48)       { W = qkv_w;  Wt = wt_qkv;  K = 256;  N = 768;  nt = id % 12;        kt = id / 12; }
    else if (id < 64)  { W = out_w;  Wt = wt_out;  K = 256;  N = 256;  nt = (id - 48) & 3;  kt = (id - 48) >> 2; }
    else if (id < 128) { W = fc_w;   Wt = wt_fc;   K = 256;  N = 1024; nt = (id - 64) & 15; kt = (id - 64) >> 4; }
    else               { W = proj_w; Wt = wt_proj; K = 1024; N = 256;  nt = (id - 128) & 3; kt = (id - 128) >> 2; }
    int n0 = nt * 64, k0 = kt * 64;

    int tid = threadIdx.x;
    int r  = tid >> 2;
    int c  = (tid & 3) << 4;

    const float* src = W + (size_t)(k0 + r) * N + n0 + c;
#pragma unroll
    for (int u = 0; u < 4; ++u) {
        float4 v = *reinterpret_cast<const float4*>(src + u * 4);
        T[r][c + u * 4 + 0] = f2bf(v.x);
        T[r][c + u * 4 + 1] = f2bf(v.y);
        T[r][c + u * 4 + 2] = f2bf(v.z);
        T[r][c + u * 4 + 3] = f2bf(v.w);
    }
    __syncthreads();
    s16x8 o0, o1;
#pragma unroll
    for (int j = 0; j < 8; ++j) { o0[j] = T[c + j][r]; o1[j] = T[c + 8 + j][r]; }
    short* dst = Wt + (size_t)(n0 + r) * K + k0 + c;
    *reinterpret_cast<s16x8*>(dst)     = o0;
    *reinterpret_cast<s16x8*>(dst + 8) = o1;
}

// ---------------------------------------------------------------- LayerNorm
__global__ __launch_bounds__(256) void ln_kernel(const float* __restrict__ x,
                                                 const float* __restrict__ gamma,
                                                 const float* __restrict__ beta,
                                                 short* __restrict__ out)
{
    int tid  = threadIdx.x;
    int lane = tid & 63;
    int row  = blockIdx.x * 4 + (tid >> 6);
    const float* xr = x + (size_t)row * 256;
    float4 v = *reinterpret_cast<const float4*>(xr + lane * 4);

    float s = v.x + v.y + v.z + v.w;
#pragma unroll
    for (int o = 32; o >= 1; o >>= 1) s += __shfl_xor(s, o);
    float mu = s * (1.0f / 256.0f);

    float dx = v.x - mu, dy = v.y - mu, dz = v.z - mu, dw = v.w - mu;
    float q = dx * dx + dy * dy + dz * dz + dw * dw;
#pragma unroll
    for (int o = 32; o >= 1; o >>= 1) q += __shfl_xor(q, o);
    float rstd = rsqrtf(q * (1.0f / 256.0f) + 1e-5f);

    float4 gv = *reinterpret_cast<const float4*>(gamma + lane * 4);
    float4 bv = *reinterpret_cast<const float4*>(beta + lane * 4);
    s16x4 ov;
    ov[0] = f2bf(dx * rstd * gv.x + bv.x);
    ov[1] = f2bf(dy * rstd * gv.y + bv.y);
    ov[2] = f2bf(dz * rstd * gv.z + bv.z);
    ov[3] = f2bf(dw * rstd * gv.w + bv.w);
    *reinterpret_cast<s16x4*>(out + (size_t)row * 256 + lane * 4) = ov;
}

// ---------------------------------------------------------------- MFMA GEMM
// QKV=1: q,k cols [0,512) -> qk_buf stride 512; v cols [512,768) -> vt_buf
// [bh][d][s] (V transposed at the source so attention never transposes).
template <int RELU, int RES, int OBF16, int BM, int QKV>
__global__ __launch_bounds__(256) void mgemm_kernel(const short* __restrict__ A,
                                                    const short* __restrict__ Bt,
                                                    const float* __restrict__ bias,
                                                    const float* __restrict__ R,
                                                    void* __restrict__ Cv,
                                                    short* __restrict__ vt,
                                                    int N, int K)
{
    constexpr int MI = BM / 32;
    __shared__ short As[BM * 64];
    __shared__ short Bs[128 * 64];

    int tid = threadIdx.x;
    int l   = tid & 63;
    int w   = tid >> 6;
    int lr  = l & 15;
    int lk8 = (l >> 4) << 3;
    int r4  = (l >> 4) << 2;
    int wr  = w >> 1, wc = w & 1;
    int bn  = blockIdx.x * 128, bm = blockIdx.y * BM;

    int scolS = ((l & 7) << 3) ^ ((l >> 3) << 3);
    int srowA = w * (BM / 4) + (l >> 3);
    int srowB = (w << 5) + (l >> 3);
    const short* pa = A  + (size_t)(bm + srowA) * K + scolS;
    const short* pb = Bt + (size_t)(bn + srowB) * K + scolS;
    short* dstA = As + w * (BM / 4) * 64;
    short* dstB = Bs + (w << 11);

    f32x4 acc[MI][4];
#pragma unroll
    for (int mi = 0; mi < MI; ++mi)
#pragma unroll
        for (int ni = 0; ni < 4; ++ni) acc[mi][ni] = (f32x4){0.f, 0.f, 0.f, 0.f};

    int swz = (lr & 7) << 3;

    for (int k0 = 0; k0 < K; k0 += 64) {
        __syncthreads();
#pragma unroll
        for (int i = 0; i < BM / 32; ++i)
            gload16(pa + (size_t)(i * 8) * K + k0, dstA + (i << 9));
#pragma unroll
        for (int i = 0; i < 4; ++i)
            gload16(pb + (size_t)(i * 8) * K + k0, dstB + (i << 9));
        __syncthreads();

#pragma unroll
        for (int ks = 0; ks < 2; ++ks) {
            s16x8 af[MI], bf[4];
#pragma unroll
            for (int mi = 0; mi < MI; ++mi) {
                int row = wr * (BM / 2) + (mi << 4) + lr;
                af[mi] = *reinterpret_cast<const s16x8*>(
                    &As[(row << 6) + (((ks << 5) + lk8) ^ swz)]);
            }
#pragma unroll
            for (int ni = 0; ni < 4; ++ni) {
                int row = (wc << 6) + (ni << 4) + lr;
                bf[ni] = *reinterpret_cast<const s16x8*>(
                    &Bs[(row << 6) + (((ks << 5) + lk8) ^ swz)]);
            }
#pragma unroll
            for (int mi = 0; mi < MI; ++mi)
#pragma unroll
                for (int ni = 0; ni < 4; ++ni)
                    acc[mi][ni] = __builtin_amdgcn_mfma_f32_16x16x32_bf16(
                        af[mi], bf[ni], acc[mi][ni], 0, 0, 0);
        }
    }

    float bv[4];
#pragma unroll
    for (int ni = 0; ni < 4; ++ni)
        bv[ni] = bias[bn + (wc << 6) + (ni << 4) + lr];

#pragma unroll
    for (int mi = 0; mi < MI; ++mi) {
#pragma unroll
        for (int ni = 0; ni < 4; ++ni) {
            int n = bn + (wc << 6) + (ni << 4) + lr;
#pragma unroll
            for (int r = 0; r < 4; ++r) {
                int m = bm + wr * (BM / 2) + (mi << 4) + r4 + r;
                float v = acc[mi][ni][r] + bv[ni];
                if (RELU) v = fmaxf(v, 0.0f);
                if (RES)  v += R[(size_t)m * N + n];
                if (QKV) {
                    if (bn < 512) {           // block-uniform branch
                        ((short*)Cv)[(size_t)m * 512 + n] = f2bf(v);
                    } else {
                        int hh = (n - 512) >> 6, dd = (n - 512) & 63;
                        int bb = m >> 10, ss = m & 1023;
                        vt[(size_t)((((bb << 2) | hh) << 6) | dd) * 1024 + ss] = f2bf(v);
                    }
                } else if (OBF16) {
                    ((short*)Cv)[(size_t)m * N + n] = f2bf(v);
                } else {
                    ((float*)Cv)[(size_t)m * N + n] = v;
                }
            }
        }
    }
}

// ------------------------------------- fused out-proj + residual + LN2
__global__ __launch_bounds__(256) void oproj_ln_kernel(const short* __restrict__ A,
                                                       const short* __restrict__ Bt,
                                                       const float* __restrict__ bias,
                                                       const float* __restrict__ R,
                                                       float* __restrict__ x1,
                                                       short* __restrict__ h2,
                                                       const float* __restrict__ g,
                                                       const float* __restrict__ bb)
{
    __shared__ short As[64 * 64];
    __shared__ short Bs[256 * 64];

    int tid = threadIdx.x;
    int l   = tid & 63;
    int w   = tid >> 6;
    int lr  = l & 15;
    int lk8 = (l >> 4) << 3;
    int r4  = (l >> 4) << 2;
    int bm  = blockIdx.x * 64;

    int scolS = ((l & 7) << 3) ^ ((l >> 3) << 3);
    const short* pa = A  + (size_t)(bm + (w << 4) + (l >> 3)) * 256 + scolS;
    const short* pb = Bt + (size_t)((w << 6) + (l >> 3)) * 256 + scolS;
    short* dstA = As + (w << 10);
    short* dstB = Bs + (w << 12);

    f32x4 acc[16];
#pragma unroll
    for (int ni = 0; ni < 16; ++ni) acc[ni] = (f32x4){0.f, 0.f, 0.f, 0.f};

    int swz = (lr & 7) << 3;

    for (int k0 = 0; k0 < 256; k0 += 64) {
        __syncthreads();
#pragma unroll
        for (int i = 0; i < 2; ++i)
            gload16(pa + (size_t)(i * 8) * 256 + k0, dstA + (i << 9));
#pragma unroll
        for (int i = 0; i < 8; ++i)
            gload16(pb + (size_t)(i * 8) * 256 + k0, dstB + (i << 9));
        __syncthreads();

#pragma unroll
        for (int ks = 0; ks < 2; ++ks) {
            int arow = (w << 4) + lr;
            s16x8 af = *reinterpret_cast<const s16x8*>(
                &As[(arow << 6) + (((ks << 5) + lk8) ^ swz)]);
#pragma unroll
            for (int ni = 0; ni < 16; ++ni) {
                int row = (ni << 4) + lr;
                s16x8 bf = *reinterpret_cast<const s16x8*>(
                    &Bs[(row << 6) + (((ks << 5) + lk8) ^ swz)]);
                acc[ni] = __builtin_amdgcn_mfma_f32_16x16x32_bf16(af, bf, acc[ni], 0, 0, 0);
            }
        }
    }

#pragma unroll
    for (int ni = 0; ni < 16; ++ni) {
        int n = (ni << 4) + lr;
        float bvx = bias[n];
#pragma unroll
        for (int r = 0; r < 4; ++r) {
            int m = bm + (w << 4) + r4 + r;
            acc[ni][r] += bvx + R[(size_t)m * 256 + n];
        }
    }
#pragma unroll
    for (int r = 0; r < 4; ++r) {
        float s = 0.0f;
#pragma unroll
        for (int ni = 0; ni < 16; ++ni) s += acc[ni][r];
        s += __shfl_xor(s, 1); s += __shfl_xor(s, 2);
        s += __shfl_xor(s, 4); s += __shfl_xor(s, 8);
        float mu = s * (1.0f / 256.0f);
        float q = 0.0f;
#pragma unroll
        for (int ni = 0; ni < 16; ++ni) {
            float d = acc[ni][r] - mu;
            q += d * d;
        }
        q += __shfl_xor(q, 1); q += __shfl_xor(q, 2);
        q += __shfl_xor(q, 4); q += __shfl_xor(q, 8);
        float rstd = rsqrtf(q * (1.0f / 256.0f) + 1e-5f);

        int m = bm + (w << 4) + r4 + r;
#pragma unroll
        for (int ni = 0; ni < 16; ++ni) {
            int n = (ni << 4) + lr;
            float v = acc[ni][r];
            x1[(size_t)m * 256 + n] = v;
            h2[(size_t)m * 256 + n] = f2bf((v - mu) * rstd * g[n] + bb[n]);
        }
    }
}

// ---------------------------------------------------------------- Attention
// Swapped-QK^T flash attention, KVBLK=64, paired q-tiles (pair, 15-pair) =
// 17 balanced kt-iters/block. 2-phase double-buffered K/V staging via
// global_load_lds (linear dest + pre-swizzled source); V^T comes pre-
// transposed from the qkv GEMM so K and V staging are identical. Softmax
// fully in-register (lane owns q=lane&15); P->PV A-frag via cvt_pk+permlane.
// Grid 512 = 8 xcd x 8 pair x 8 bhg; all blocks of one (b,h) share an XCD.
__global__ __launch_bounds__(256, 2) void attn_kernel(const short* __restrict__ qk,
                                                      const short* __restrict__ vt,
                                                      short* __restrict__ o)
{
    __shared__ short Ks[2][64 * 64];
    __shared__ short Vs[2][64 * 64];

    int bid  = blockIdx.x;
    int xcd  = bid & 7;
    int pair = (bid >> 3) & 7;
    int bhg  = bid >> 6;             // 0..7
    int bh   = (bhg << 3) | xcd;
    int b = bh >> 2, h = bh & 3;

    int tid = threadIdx.x;
    int l   = tid & 63;
    int w   = tid >> 6;
    int lr  = l & 15;
    int g   = l >> 4;
    int lk8 = g << 3;
    int w16 = w << 4;

    // staging constants: lane covers K/V tile row (w*8 + l>>3) (+i*32),
    // 16B at source col pre-swizzled so linear LDS dest + swizzled read match.
    int srow = (w << 3) + (l >> 3);
    int scol = ((l & 7) << 3) ^ (((l >> 3) & 7) << 3);
    const short* kgp = qk + (size_t)(b * 1024 + srow) * 512 + 256 + h * 64 + scol;
    const short* vgp = vt + (size_t)((bh << 6) + srow) * 1024 + scol;
    short* dstK = &Ks[0][(w << 3) * 64];
    short* dstV = &Vs[0][(w << 3) * 64];
    const int BUFS = 64 * 64;        // shorts per buffer

    const float SC = 0.125f * 1.44269504088896f;   // 1/sqrt(D) * log2(e)
    int rsw = (lr & 7) << 3;

    int cur = 1;
    for (int sel = 0; sel < 2; ++sel) {
        int qt = sel == 0 ? pair : 15 - pair;

        // Q fragments straight from global (no LDS)
        const short* qrow = qk + (size_t)(b * 1024 + qt * 64 + w16 + lr) * 512 + h * 64;
        s16x8 qf[2];
        qf[0] = *reinterpret_cast<const s16x8*>(qrow + lk8);
        qf[1] = *reinterpret_cast<const s16x8*>(qrow + 32 + lk8);

        // stage kt=0 into buffer cur^1 (prior tile's last reads already done)
#pragma unroll
        for (int i = 0; i < 2; ++i) {
            gload16(kgp + (size_t)(qt * 0 + i * 32) * 512, dstK + (cur ^ 1) * BUFS + (i << 11));
            gload16(vgp + (size_t)(i * 32) * 1024,         dstV + (cur ^ 1) * BUFS + (i << 11));
        }
        __syncthreads();
        cur ^= 1;

        float m = -1e30f, lsum = 0.0f;
        f32x4 oacc[4];
#pragma unroll
        for (int dt = 0; dt < 4; ++dt) oacc[dt] = (f32x4){0.f, 0.f, 0.f, 0.f};
        int qglob = qt * 64 + w16 + lr;

        for (int kt = 0; kt <= qt; ++kt) {
            // ---- issue next tile's loads (latency hides under compute) ----
            if (kt < qt) {
#pragma unroll
                for (int i = 0; i < 2; ++i) {
                    gload16(kgp + (size_t)((kt + 1) * 64 + i * 32) * 512,
                            dstK + (cur ^ 1) * BUFS + (i << 11));
                    gload16(vgp + (size_t)(i * 32) * 1024 + (kt + 1) * 64,
                            dstV + (cur ^ 1) * BUFS + (i << 11));
                }
            }

            // ---- S^T = K Q^T ----
            f32x4 s[4];
#pragma unroll
            for (int jt = 0; jt < 4; ++jt) s[jt] = (f32x4){0.f, 0.f, 0.f, 0.f};
#pragma unroll
            for (int ks = 0; ks < 2; ++ks) {
#pragma unroll
                for (int jt = 0; jt < 4; ++jt) {
                    int row = jt * 16 + lr;
                    s16x8 kf = *reinterpret_cast<const s16x8*>(
                        &Ks[cur][(row << 6) + ((32 * ks + lk8) ^ rsw)]);
                    s[jt] = __builtin_amdgcn_mfma_f32_16x16x32_bf16(kf, qf[ks], s[jt], 0, 0, 0);
                }
            }
#pragma unroll
            for (int jt = 0; jt < 4; ++jt)
#pragma unroll
                for (int r = 0; r < 4; ++r) s[jt][r] *= SC;

            if (kt == qt) {          // causal mask on diagonal tile
#pragma unroll
                for (int jt = 0; jt < 4; ++jt) {
                    int kb = kt * 64 + jt * 16 + (g << 2);
#pragma unroll
                    for (int r = 0; r < 4; ++r)
                        if (kb + r > qglob) s[jt][r] = -1e30f;
                }
            }

            // ---- in-register online softmax (lane owns q = qglob) ----
            float rm = fmaxf(fmaxf(s[0][0], s[0][1]), fmaxf(s[0][2], s[0][3]));
#pragma unroll
            for (int jt = 1; jt < 4; ++jt)
                rm = fmaxf(rm, fmaxf(fmaxf(s[jt][0], s[jt][1]), fmaxf(s[jt][2], s[jt][3])));
            rm = fmaxf(rm, __shfl_xor(rm, 16));
            rm = fmaxf(rm, __shfl_xor(rm, 32));
            float mn  = fmaxf(m, rm);
            float fct = exp2f(m - mn);
            m = mn;
            float ps = 0.0f;
#pragma unroll
            for (int jt = 0; jt < 4; ++jt)
#pragma unroll
                for (int r = 0; r < 4; ++r) {
                    float p = exp2f(s[jt][r] - mn);
                    s[jt][r] = p;
                    ps += p;
                }
            ps += __shfl_xor(ps, 16);
            ps += __shfl_xor(ps, 32);
            lsum = lsum * fct + ps;

            int cpk[4][2];
#pragma unroll
            for (int jt = 0; jt < 4; ++jt) {
                cpk[jt][0] = cvt_pk_bf16(s[jt][0], s[jt][1]);
                cpk[jt][1] = cvt_pk_bf16(s[jt][2], s[jt][3]);
            }

#pragma unroll
            for (int r = 0; r < 4; ++r) {
                float f4 = __shfl(fct, 4 * g + r);
#pragma unroll
                for (int dt = 0; dt < 4; ++dt) oacc[dt][r] *= f4;
            }

            // ---- O += P V ----
#pragma unroll
            for (int ks = 0; ks < 2; ++ks) {
                int a0 = cpk[2 * ks][0],     a1 = cpk[2 * ks][1];
                int b0 = cpk[2 * ks + 1][0], b1 = cpk[2 * ks + 1][1];
                swap32(a0, b0); swap32(a1, b1);
                swap16(a0, b0); swap16(a1, b1);
                union { int i[4]; s16x8 v; } fr;
                fr.i[0] = a0; fr.i[1] = a1; fr.i[2] = b0; fr.i[3] = b1;
#pragma unroll
                for (int dt = 0; dt < 4; ++dt) {
                    int row = dt * 16 + lr;
                    s16x8 vf = *reinterpret_cast<const s16x8*>(
                        &Vs[cur][(row << 6) + ((32 * ks + lk8) ^ rsw)]);
                    oacc[dt] = __builtin_amdgcn_mfma_f32_16x16x32_bf16(fr.v, vf, oacc[dt], 0, 0, 0);
                }
            }

            if (kt < qt) {
                __syncthreads();     // publishes stage(kt+1); vmcnt drained here
                cur ^= 1;
            }
        }

        // ---- finalize: O[q=4g+r][d=16dt+lr] /= lsum[q], store bf16 ----
#pragma unroll
        for (int r = 0; r < 4; ++r) {
            float lv  = __shfl(lsum, 4 * g + r);
            float inv = 1.0f / lv;
            short* orow = o + (size_t)(b * 1024 + qt * 64 + w16 + 4 * g + r) * 256 + h * 64;
#pragma unroll
            for (int dt = 0; dt < 4; ++dt)
                orow[dt * 16 + lr] = f2bf(oacc[dt][r] * inv);
        }
    }
}

// ---------------------------------------------------------------- launch
extern "C" void kernel_launch(void* const* d_in, const int* in_sizes, int n_in,
                              void* d_out, int out_size, void* d_ws, size_t ws_size,
                              hipStream_t stream)
{
    const float* x      = (const float*)d_in[0];
    const float* qkv_w  = (const float*)d_in[1];
    const float* qkv_b  = (const float*)d_in[2];
    const float* out_w  = (const float*)d_in[3];
    const float* out_b  = (const float*)d_in[4];
    const float* fc_w   = (const float*)d_in[5];
    const float* fc_b   = (const float*)d_in[6];
    const float* proj_w = (const float*)d_in[7];
    const float* proj_b = (const float*)d_in[8];
    const float* ln1_g  = (const float*)d_in[9];
    const float* ln1_b  = (const float*)d_in[10];
    const float* ln2_g  = (const float*)d_in[11];
    const float* ln2_b  = (const float*)d_in[12];
    float* out = (float*)d_out;

    short* ws = (short*)d_ws;
    short* wt_qkv  = ws;                     // [768][256]
    short* wt_out  = ws + 196608;            // [256][256]
    short* wt_fc   = ws + 262144;            // [1024][256]
    short* wt_proj = ws + 524288;            // [256][1024]
    short* bufA    = ws + 786432;            // [T,256] bf16 (h / o / h2)
    short* qk_buf  = ws + 4980736;           // [T,512] bf16 (q,k)
    short* vt_buf  = ws + 13369344;          // [64][64][1024] bf16 (V^T per bh)
    short* h3_buf  = ws + 4980736;           // [T,1024] overlays qk+vt (dead)

    dim3 blk(256);

    // 0. weight convert+transpose
    wconv_all_kernel<<<dim3(192), blk, 0, stream>>>(
        qkv_w, out_w, fc_w, proj_w, wt_qkv, wt_out, wt_fc, wt_proj);
    // 1. h = LN1(x)
    ln_kernel<<<dim3(4096), blk, 0, stream>>>(x, ln1_g, ln1_b, bufA);
    // 2. qkv = h @ qkv_w + qkv_b   -> qk_buf + vt_buf (V transposed at source)
    mgemm_kernel<0, 0, 1, 128, 1><<<dim3(6, 128), blk, 0, stream>>>(
        bufA, wt_qkv, qkv_b, nullptr, qk_buf, vt_buf, 768, 256);
    // 3. o = attention(qk, vt)
    attn_kernel<<<dim3(512), blk, 0, stream>>>(qk_buf, vt_buf, bufA);
    // 4. x1 = x + o@out_w+out_b -> d_out ; h2 = LN2(x1) -> bufA  (fused)
    oproj_ln_kernel<<<dim3(256), blk, 0, stream>>>(
        bufA, wt_out, out_b, x, out, bufA, ln2_g, ln2_b);
    // 5. h3 = relu(h2 @ fc_w + fc_b)
    mgemm_kernel<1, 0, 1, 128, 0><<<dim3(8, 128), blk, 0, stream>>>(
        bufA, wt_fc, fc_b, nullptr, h3_buf, nullptr, 1024, 256);
    // 6. out = x1 + h3 @ proj_w + proj_b (in-place residual on d_out)
    mgemm_kernel<0, 1, 0, 64, 0><<<dim3(2, 256), blk, 0, stream>>>(
        h3_buf, wt_proj, proj_b, out, out, nullptr, 256, 1024);
}